// Round 1
// baseline (1999.161 us; speedup 1.0000x reference)
//
#include <hip/hip_runtime.h>
#include <hip/hip_bf16.h>
#include <math.h>

// Problem constants
#define BB 2
#define TT 1024
#define CC 1024
#define HH 16
#define DD 64
#define EE 16
#define II 256
#define NN (BB*TT)          // 2048 tokens
#define EPSLN 1e-5f

// ---------------------------------------------------------------------------
// LayerNorm: one block per row of 1024
// ---------------------------------------------------------------------------
__global__ __launch_bounds__(256) void ln_kernel(const float* __restrict__ x,
                                                 const float* __restrict__ g,
                                                 const float* __restrict__ bta,
                                                 float* __restrict__ out) {
    const int row = blockIdx.x, tid = threadIdx.x;
    __shared__ float r1[256], r2[256];
    const float* xr = x + (long)row * CC;
    float4 xv = ((const float4*)xr)[tid];
    float s  = xv.x + xv.y + xv.z + xv.w;
    float q2 = xv.x*xv.x + xv.y*xv.y + xv.z*xv.z + xv.w*xv.w;
    r1[tid] = s; r2[tid] = q2; __syncthreads();
    for (int st = 128; st > 0; st >>= 1) {
        if (tid < st) { r1[tid] += r1[tid+st]; r2[tid] += r2[tid+st]; }
        __syncthreads();
    }
    const float mu  = r1[0] * (1.f/CC);
    const float var = r2[0] * (1.f/CC) - mu*mu;
    const float rs  = rsqrtf(var + EPSLN);
    float4 gv = ((const float4*)g)[tid];
    float4 bv = ((const float4*)bta)[tid];
    float4 ov;
    ov.x = (xv.x-mu)*rs*gv.x + bv.x;
    ov.y = (xv.y-mu)*rs*gv.y + bv.y;
    ov.z = (xv.z-mu)*rs*gv.z + bv.z;
    ov.w = (xv.w-mu)*rs*gv.w + bv.w;
    ((float4*)(out + (long)row * CC))[tid] = ov;
}

// ---------------------------------------------------------------------------
// fp32 tiled GEMM, 64x64 tile, 16-deep K slab, 256 threads, 4x4 per thread.
// A [M,K] row-major, B [K,N] row-major. Batched over blockIdx.z (experts).
// EPI: 0 = plain, 1 = +resid, 2 = exact gelu, 3 = *mask (strided output)
// ---------------------------------------------------------------------------
template<int EPI>
__global__ __launch_bounds__(256) void gemm64(
        const float* __restrict__ A, long sAe,
        const float* __restrict__ B, long sBe,
        float* __restrict__ Cp, long sCe, int ldc,
        int M, int N, int K,
        const float* __restrict__ resid,
        const float* __restrict__ mask, int Enum) {
    const int e = blockIdx.z;
    A  += (long)e * sAe;
    B  += (long)e * sBe;
    Cp += (long)e * sCe;
    const int n0 = blockIdx.x * 64, m0 = blockIdx.y * 64;
    const int tid = threadIdx.x, tx = tid & 15, ty = tid >> 4;
    __shared__ float As[16][65];
    __shared__ float Bs[16][64];
    float acc[4][4] = {};
    for (int k0 = 0; k0 < K; k0 += 16) {
        #pragma unroll
        for (int i = 0; i < 4; i++) {
            int lin = tid + i*256;
            int mm = lin >> 4, kk = lin & 15;
            As[kk][mm] = A[(long)(m0+mm)*K + k0 + kk];
            int nn = lin & 63, kb = lin >> 6;
            Bs[kb][nn] = B[(long)(k0+kb)*N + n0 + nn];
        }
        __syncthreads();
        #pragma unroll
        for (int kk = 0; kk < 16; kk++) {
            float a[4], bb[4];
            #pragma unroll
            for (int i = 0; i < 4; i++) a[i] = As[kk][ty*4+i];
            #pragma unroll
            for (int j = 0; j < 4; j++) bb[j] = Bs[kk][tx*4+j];
            #pragma unroll
            for (int i = 0; i < 4; i++)
                #pragma unroll
                for (int j = 0; j < 4; j++)
                    acc[i][j] += a[i]*bb[j];
        }
        __syncthreads();
    }
    #pragma unroll
    for (int i = 0; i < 4; i++) {
        const int row = m0 + ty*4 + i;
        float mv = 1.f;
        if (EPI == 3) mv = mask[(long)row*Enum + e];
        #pragma unroll
        for (int j = 0; j < 4; j++) {
            const int col = n0 + tx*4 + j;
            float val = acc[i][j];
            if (EPI == 1) val += resid[(long)row*N + col];
            if (EPI == 2) val = 0.5f*val*(1.f + erff(val*0.70710678118f));
            if (EPI == 3) val *= mv;
            Cp[(long)row*ldc + col] = val;
        }
    }
}

// ---------------------------------------------------------------------------
// Causal attention: one block per (b, h, q-row). Full logits row in LDS.
// q/k/v layout: [b, t, h, d] flat == [N, C] row-major with head offset h*64.
// ---------------------------------------------------------------------------
__global__ __launch_bounds__(256) void attn_kernel(const float* __restrict__ q,
                                                   const float* __restrict__ k,
                                                   const float* __restrict__ v,
                                                   float* __restrict__ o) {
    __shared__ float sl[TT];
    __shared__ float qs[DD];
    __shared__ float red[256];
    __shared__ float pv[4][DD];
    const int tq = blockIdx.x, h = blockIdx.y, b = blockIdx.z;
    const int tid = threadIdx.x;
    const long base_bh = (long)b * TT * CC + h * DD;
    const float* qrow = q + base_bh + (long)tq * CC;
    if (tid < DD) qs[tid] = qrow[tid];
    __syncthreads();
    const int nk = tq + 1;
    float lmax = -1e30f;
    for (int kk = tid; kk < nk; kk += 256) {
        const float* kr = k + base_bh + (long)kk * CC;
        float dot = 0.f;
        #pragma unroll
        for (int d = 0; d < DD; d += 4)
            dot += qs[d]*kr[d] + qs[d+1]*kr[d+1] + qs[d+2]*kr[d+2] + qs[d+3]*kr[d+3];
        dot *= 0.125f;   // 1/sqrt(64)
        sl[kk] = dot;
        lmax = fmaxf(lmax, dot);
    }
    red[tid] = lmax; __syncthreads();
    for (int s = 128; s > 0; s >>= 1) {
        if (tid < s) red[tid] = fmaxf(red[tid], red[tid+s]);
        __syncthreads();
    }
    const float m = red[0];
    __syncthreads();
    float lsum = 0.f;
    for (int kk = tid; kk < nk; kk += 256) {
        float p = expf(sl[kk] - m);
        sl[kk] = p;
        lsum += p;
    }
    red[tid] = lsum; __syncthreads();
    for (int s = 128; s > 0; s >>= 1) {
        if (tid < s) red[tid] += red[tid+s];
        __syncthreads();
    }
    const float inv = 1.f / red[0];
    // PV: 4 groups of 64 lanes, each group strides over k rows
    const int g = tid >> 6, d = tid & 63;
    float acc = 0.f;
    for (int kk = g; kk < nk; kk += 4)
        acc += sl[kk] * v[base_bh + (long)kk * CC + d];
    pv[g][d] = acc;
    __syncthreads();
    if (tid < DD) {
        float r = (pv[0][tid] + pv[1][tid] + pv[2][tid] + pv[3][tid]) * inv;
        o[base_bh + (long)tq * CC + tid] = r;
    }
}

// ---------------------------------------------------------------------------
// Column norms of sim_matrix [C, E]: one block per expert column
// ---------------------------------------------------------------------------
__global__ __launch_bounds__(256) void colnorm_kernel(const float* __restrict__ sim,
                                                      float* __restrict__ cn) {
    const int e = blockIdx.x, tid = threadIdx.x;
    __shared__ float red[256];
    float s = 0.f;
    for (int c = tid; c < CC; c += 256) {
        float vv = sim[(long)c*EE + e];
        s += vv*vv;
    }
    red[tid] = s; __syncthreads();
    for (int st = 128; st > 0; st >>= 1) {
        if (tid < st) red[tid] += red[tid+st];
        __syncthreads();
    }
    if (tid == 0) cn[e] = sqrtf(red[0]);
}

// ---------------------------------------------------------------------------
// Router: scores, mask, k_per_token. One block per token.
// ---------------------------------------------------------------------------
__global__ __launch_bounds__(256) void scores_kernel(const float* __restrict__ h2,
                                                     const float* __restrict__ sim,
                                                     const float* __restrict__ cn,
                                                     const float* __restrict__ thr,
                                                     float* __restrict__ scores,
                                                     float* __restrict__ kpt,
                                                     float* __restrict__ maskb) {
    const int row = blockIdx.x, tid = threadIdx.x;
    __shared__ float red[256*17];
    float acc[17] = {};                 // 16 dots + |x|^2 in [16]
    for (int c = tid; c < CC; c += 256) {
        const float xv = h2[(long)row*CC + c];
        acc[16] += xv*xv;
        const float* sr = sim + (long)c*EE;
        #pragma unroll
        for (int e2 = 0; e2 < EE; e2++) acc[e2] += xv*sr[e2];
    }
    #pragma unroll
    for (int e2 = 0; e2 < 17; e2++) red[tid*17 + e2] = acc[e2];
    __syncthreads();
    for (int st = 128; st > 0; st >>= 1) {
        if (tid < st)
            for (int e2 = 0; e2 < 17; e2++) red[tid*17+e2] += red[(tid+st)*17+e2];
        __syncthreads();
    }
    if (tid < EE) {
        const float nrm = sqrtf(red[16]);
        const float sc  = red[tid] / (nrm * cn[tid]);
        scores[(long)row*EE + tid] = sc;
        const float mkv = sc > thr[0] ? 1.f : 0.f;
        maskb[(long)row*EE + tid] = mkv;
        red[tid] = mkv;
    }
    __syncthreads();
    if (tid == 0) {
        float c2 = 0.f;
        for (int e2 = 0; e2 < EE; e2++) c2 += red[e2];
        kpt[row] = c2;
    }
}

// ---------------------------------------------------------------------------
// final[n,c] = sum_e eo[n,e,c] (already masked); x_out += final, in place
// ---------------------------------------------------------------------------
__global__ __launch_bounds__(256) void moe_sum_kernel(const float* __restrict__ eo,
                                                      float* __restrict__ xio) {
    const int row = blockIdx.x, tid = threadIdx.x;
    for (int c = tid; c < CC; c += 256) {
        float s = 0.f;
        #pragma unroll
        for (int e2 = 0; e2 < EE; e2++)
            s += eo[((long)row*EE + e2)*CC + c];
        xio[(long)row*CC + c] += s;
    }
}

// ---------------------------------------------------------------------------
extern "C" void kernel_launch(void* const* d_in, const int* in_sizes, int n_in,
                              void* d_out, int out_size, void* d_ws, size_t ws_size,
                              hipStream_t stream) {
    const float* x     = (const float*)d_in[0];
    const float* ln1_g = (const float*)d_in[1];
    const float* ln1_b = (const float*)d_in[2];
    const float* ln2_g = (const float*)d_in[3];
    const float* ln2_b = (const float*)d_in[4];
    const float* wq    = (const float*)d_in[5];
    const float* wk    = (const float*)d_in[6];
    const float* wv    = (const float*)d_in[7];
    const float* wo    = (const float*)d_in[8];
    const float* sim   = (const float*)d_in[9];
    const float* thr   = (const float*)d_in[10];
    const float* w1    = (const float*)d_in[11];
    const float* w2    = (const float*)d_in[12];

    // d_out layout: x[2M] | scores[32K] | expert_outputs_full[33.5M] | k_per_token[2K]
    float* out_x      = (float*)d_out;
    float* out_scores = out_x + (long)NN*CC;
    float* out_eo     = out_scores + (long)NN*EE;
    float* out_kpt    = out_eo + (long)NN*EE*CC;

    float* ws   = (float*)d_ws;
    float* h    = ws;                          // 2M floats
    float* qb   = ws + 1L*NN*CC;
    float* kb   = ws + 2L*NN*CC;
    float* vb   = ws + 3L*NN*CC;
    float* ao   = ws + 4L*NN*CC;
    float* h2   = ws + 5L*NN*CC;
    float* mid  = ws + 6L*NN*CC;               // E*N*I = 8M floats
    float* maskb = mid + (long)EE*NN*II;       // 32K
    float* cn    = maskb + (long)NN*EE;        // 16

    // 1. LN1
    ln_kernel<<<NN, 256, 0, stream>>>(x, ln1_g, ln1_b, h);

    // 2. QKV projections
    dim3 gqkv(CC/64, NN/64, 1);
    gemm64<0><<<gqkv, 256, 0, stream>>>(h, 0, wq, 0, qb, 0, CC, NN, CC, CC, nullptr, nullptr, EE);
    gemm64<0><<<gqkv, 256, 0, stream>>>(h, 0, wk, 0, kb, 0, CC, NN, CC, CC, nullptr, nullptr, EE);
    gemm64<0><<<gqkv, 256, 0, stream>>>(h, 0, wv, 0, vb, 0, CC, NN, CC, CC, nullptr, nullptr, EE);

    // 3. causal attention
    dim3 gattn(TT, HH, BB);
    attn_kernel<<<gattn, 256, 0, stream>>>(qb, kb, vb, ao);

    // 4. output projection + residual -> d_out x slot
    gemm64<1><<<gqkv, 256, 0, stream>>>(ao, 0, wo, 0, out_x, 0, CC, NN, CC, CC, x, nullptr, EE);

    // 5. LN2
    ln_kernel<<<NN, 256, 0, stream>>>(out_x, ln2_g, ln2_b, h2);

    // 6. router
    colnorm_kernel<<<EE, 256, 0, stream>>>(sim, cn);
    scores_kernel<<<NN, 256, 0, stream>>>(h2, sim, cn, thr, out_scores, out_kpt, maskb);

    // 7. expert GEMM 1: mid[e] = gelu(h2 @ w1[e])   [N x I per expert]
    dim3 gw1(II/64, NN/64, EE);
    gemm64<2><<<gw1, 256, 0, stream>>>(h2, 0, w1, (long)CC*II, mid, (long)NN*II, II,
                                       NN, II, CC, nullptr, nullptr, EE);

    // 8. expert GEMM 2: eo[n,e,:] = (mid[e] @ w2[e]) * mask[n,e]  (strided into d_out)
    dim3 gw2(CC/64, NN/64, EE);
    gemm64<3><<<gw2, 256, 0, stream>>>(mid, (long)NN*II, w2, (long)II*CC, out_eo, (long)CC, EE*CC,
                                       NN, CC, II, nullptr, maskb, EE);

    // 9. final = sum_e eo; x += final (in place on d_out)
    moe_sum_kernel<<<NN, 256, 0, stream>>>(out_eo, out_x);
}

// Round 2
// 1359.447 us; speedup vs baseline: 1.4706x; 1.4706x over previous
//
#include <hip/hip_runtime.h>
#include <hip/hip_bf16.h>
#include <math.h>

// Problem constants
#define BB 2
#define TT 1024
#define CC 1024
#define HH 16
#define DD 64
#define EE 16
#define II 256
#define NN (BB*TT)          // 2048 tokens
#define EPSLN 1e-5f
#define PADL 68             // LDS row stride (floats): 68*4B = 272B = 16B-aligned, odd*4 mod 32 banks

// ---------------------------------------------------------------------------
// LayerNorm: one block per row of 1024
// ---------------------------------------------------------------------------
__global__ __launch_bounds__(256) void ln_kernel(const float* __restrict__ x,
                                                 const float* __restrict__ g,
                                                 const float* __restrict__ bta,
                                                 float* __restrict__ out) {
    const int row = blockIdx.x, tid = threadIdx.x;
    __shared__ float r1[256], r2[256];
    const float* xr = x + (long)row * CC;
    float4 xv = ((const float4*)xr)[tid];
    float s  = xv.x + xv.y + xv.z + xv.w;
    float q2 = xv.x*xv.x + xv.y*xv.y + xv.z*xv.z + xv.w*xv.w;
    r1[tid] = s; r2[tid] = q2; __syncthreads();
    for (int st = 128; st > 0; st >>= 1) {
        if (tid < st) { r1[tid] += r1[tid+st]; r2[tid] += r2[tid+st]; }
        __syncthreads();
    }
    const float mu  = r1[0] * (1.f/CC);
    const float var = r2[0] * (1.f/CC) - mu*mu;
    const float rs  = rsqrtf(var + EPSLN);
    float4 gv = ((const float4*)g)[tid];
    float4 bv = ((const float4*)bta)[tid];
    float4 ov;
    ov.x = (xv.x-mu)*rs*gv.x + bv.x;
    ov.y = (xv.y-mu)*rs*gv.y + bv.y;
    ov.z = (xv.z-mu)*rs*gv.z + bv.z;
    ov.w = (xv.w-mu)*rs*gv.w + bv.w;
    ((float4*)(out + (long)row * CC))[tid] = ov;
}

// ---------------------------------------------------------------------------
// fp32 tiled GEMM, 64x64 tile, 16-deep K slab, 256 threads, 4x4 per thread.
// A [M,K] row-major, B [K,N] row-major. Batched over blockIdx.z (experts).
// EPI: 0 = plain, 1 = +resid, 2 = exact gelu, 3 = *mask (strided output)
// ---------------------------------------------------------------------------
template<int EPI>
__global__ __launch_bounds__(256) void gemm64(
        const float* __restrict__ A, long sAe,
        const float* __restrict__ B, long sBe,
        float* __restrict__ Cp, long sCe, int ldc,
        int M, int N, int K,
        const float* __restrict__ resid,
        const float* __restrict__ mask, int Enum) {
    const int e = blockIdx.z;
    A  += (long)e * sAe;
    B  += (long)e * sBe;
    Cp += (long)e * sCe;
    const int n0 = blockIdx.x * 64, m0 = blockIdx.y * 64;
    const int tid = threadIdx.x, tx = tid & 15, ty = tid >> 4;
    __shared__ float As[16][65];
    __shared__ float Bs[16][64];
    float acc[4][4] = {};
    for (int k0 = 0; k0 < K; k0 += 16) {
        #pragma unroll
        for (int i = 0; i < 4; i++) {
            int lin = tid + i*256;
            int mm = lin >> 4, kk = lin & 15;
            As[kk][mm] = A[(long)(m0+mm)*K + k0 + kk];
            int nn = lin & 63, kb = lin >> 6;
            Bs[kb][nn] = B[(long)(k0+kb)*N + n0 + nn];
        }
        __syncthreads();
        #pragma unroll
        for (int kk = 0; kk < 16; kk++) {
            float a[4], bb[4];
            #pragma unroll
            for (int i = 0; i < 4; i++) a[i] = As[kk][ty*4+i];
            #pragma unroll
            for (int j = 0; j < 4; j++) bb[j] = Bs[kk][tx*4+j];
            #pragma unroll
            for (int i = 0; i < 4; i++)
                #pragma unroll
                for (int j = 0; j < 4; j++)
                    acc[i][j] += a[i]*bb[j];
        }
        __syncthreads();
    }
    #pragma unroll
    for (int i = 0; i < 4; i++) {
        const int row = m0 + ty*4 + i;
        float mv = 1.f;
        if (EPI == 3) mv = mask[(long)row*Enum + e];
        #pragma unroll
        for (int j = 0; j < 4; j++) {
            const int col = n0 + tx*4 + j;
            float val = acc[i][j];
            if (EPI == 1) val += resid[(long)row*N + col];
            if (EPI == 2) val = 0.5f*val*(1.f + erff(val*0.70710678118f));
            if (EPI == 3) val *= mv;
            Cp[(long)row*ldc + col] = val;
        }
    }
}

// ---------------------------------------------------------------------------
// Flash-style causal attention. One block per (b, h, 64-row q tile).
// Layouts in LDS: Qs[d][r], Ks[d][kk] (transposed), Vs[kk][c], Ps[kk][r].
// 4x4 register blocking, float4 LDS reads, online softmax.
// q/k/v layout: [b, t, h, d] flat == [N, C] row-major with head offset h*64.
// ---------------------------------------------------------------------------
__global__ __launch_bounds__(256) void attn_flash(const float* __restrict__ q,
                                                  const float* __restrict__ k,
                                                  const float* __restrict__ v,
                                                  float* __restrict__ o) {
    __shared__ __align__(16) float Qs[DD][PADL];
    __shared__ __align__(16) float Ks[DD][PADL];
    __shared__ __align__(16) float Vs[64][PADL];
    __shared__ __align__(16) float Ps[64][PADL];
    __shared__ float mrow[64], lrow[64], arow[64];

    const int qt = blockIdx.x, h = blockIdx.y, b = blockIdx.z;
    const int tid = threadIdx.x;
    const long base = (long)b * TT * CC + (long)h * DD;

    // load Q tile transposed: Qs[c][r] = Q[qt*64+r][c]
    #pragma unroll
    for (int i = 0; i < 16; i++) {
        int lin = tid + i*256;
        int r = lin >> 6, c = lin & 63;
        Qs[c][r] = q[base + (long)(qt*64 + r)*CC + c];
    }
    if (tid < 64) { mrow[tid] = -1e30f; lrow[tid] = 0.f; }

    const int g4 = tid >> 4;       // 0..15
    const int l4 = tid & 15;       // 0..15
    const int r0 = g4 * 4;         // row group (QK rows / PV rows)
    const int c0 = l4 * 4;         // col group (QK: kk cols; PV: d cols)

    float acc[4][4] = {{0.f}};

    for (int kt = 0; kt <= qt; kt++) {
        __syncthreads();   // prev-iter readers of Ks/Vs/Ps done
        #pragma unroll
        for (int i = 0; i < 16; i++) {
            int lin = tid + i*256;
            int r = lin >> 6, c = lin & 63;
            Ks[c][r] = k[base + (long)(kt*64 + r)*CC + c];
            Vs[r][c] = v[base + (long)(kt*64 + r)*CC + c];
        }
        __syncthreads();

        // scores: s[i][j] = sum_d Q[r0+i][d] * K[c0+j][d]
        float s00=0,s01=0,s02=0,s03=0, s10=0,s11=0,s12=0,s13=0;
        float s20=0,s21=0,s22=0,s23=0, s30=0,s31=0,s32=0,s33=0;
        #pragma unroll 8
        for (int d = 0; d < DD; d++) {
            float4 a  = *(const float4*)&Qs[d][r0];
            float4 bv = *(const float4*)&Ks[d][c0];
            s00 += a.x*bv.x; s01 += a.x*bv.y; s02 += a.x*bv.z; s03 += a.x*bv.w;
            s10 += a.y*bv.x; s11 += a.y*bv.y; s12 += a.y*bv.z; s13 += a.y*bv.w;
            s20 += a.z*bv.x; s21 += a.z*bv.y; s22 += a.z*bv.z; s23 += a.z*bv.w;
            s30 += a.w*bv.x; s31 += a.w*bv.y; s32 += a.w*bv.z; s33 += a.w*bv.w;
        }
        float sarr[4][4] = {{s00,s01,s02,s03},{s10,s11,s12,s13},
                            {s20,s21,s22,s23},{s30,s31,s32,s33}};
        const bool diag = (kt == qt);
        #pragma unroll
        for (int j = 0; j < 4; j++)
            #pragma unroll
            for (int i = 0; i < 4; i++) {
                int rr = r0 + i, kk = c0 + j;
                float val = sarr[i][j] * 0.125f;       // 1/sqrt(64)
                if (diag && kk > rr) val = -1e30f;
                Ps[kk][rr] = val;
            }
        __syncthreads();

        // online-softmax row pass: lane (tid<64) owns row tid
        if (tid < 64) {
            const int rr = tid;
            const float mo = mrow[rr];
            float mx = mo;
            #pragma unroll 8
            for (int kk = 0; kk < 64; kk++) mx = fmaxf(mx, Ps[kk][rr]);
            const float al = __expf(mo - mx);
            float rs = 0.f;
            #pragma unroll 8
            for (int kk = 0; kk < 64; kk++) {
                float p = __expf(Ps[kk][rr] - mx);
                Ps[kk][rr] = p;
                rs += p;
            }
            mrow[rr] = mx;
            lrow[rr] = lrow[rr] * al + rs;
            arow[rr] = al;
        }
        __syncthreads();

        // rescale O, accumulate PV: O[r0+i][c0+j] += sum_kk P[kk][r0+i]*V[kk][c0+j]
        const float al0 = arow[r0], al1 = arow[r0+1], al2 = arow[r0+2], al3 = arow[r0+3];
        #pragma unroll
        for (int j = 0; j < 4; j++) {
            acc[0][j] *= al0; acc[1][j] *= al1; acc[2][j] *= al2; acc[3][j] *= al3;
        }
        #pragma unroll 8
        for (int kk = 0; kk < 64; kk++) {
            float4 p  = *(const float4*)&Ps[kk][r0];
            float4 vv = *(const float4*)&Vs[kk][c0];
            acc[0][0] += p.x*vv.x; acc[0][1] += p.x*vv.y; acc[0][2] += p.x*vv.z; acc[0][3] += p.x*vv.w;
            acc[1][0] += p.y*vv.x; acc[1][1] += p.y*vv.y; acc[1][2] += p.y*vv.z; acc[1][3] += p.y*vv.w;
            acc[2][0] += p.z*vv.x; acc[2][1] += p.z*vv.y; acc[2][2] += p.z*vv.z; acc[2][3] += p.z*vv.w;
            acc[3][0] += p.w*vv.x; acc[3][1] += p.w*vv.y; acc[3][2] += p.w*vv.z; acc[3][3] += p.w*vv.w;
        }
    }

    // epilogue: divide by l, store coalesced float4
    const float i0 = 1.f/lrow[r0], i1 = 1.f/lrow[r0+1], i2 = 1.f/lrow[r0+2], i3 = 1.f/lrow[r0+3];
    const float invs[4] = {i0, i1, i2, i3};
    #pragma unroll
    for (int i = 0; i < 4; i++) {
        float4 ov;
        ov.x = acc[i][0]*invs[i]; ov.y = acc[i][1]*invs[i];
        ov.z = acc[i][2]*invs[i]; ov.w = acc[i][3]*invs[i];
        *(float4*)&o[base + (long)(qt*64 + r0 + i)*CC + c0] = ov;
    }
}

// ---------------------------------------------------------------------------
// Column norms of sim_matrix [C, E]: one block per expert column
// ---------------------------------------------------------------------------
__global__ __launch_bounds__(256) void colnorm_kernel(const float* __restrict__ sim,
                                                      float* __restrict__ cn) {
    const int e = blockIdx.x, tid = threadIdx.x;
    __shared__ float red[256];
    float s = 0.f;
    for (int c = tid; c < CC; c += 256) {
        float vv = sim[(long)c*EE + e];
        s += vv*vv;
    }
    red[tid] = s; __syncthreads();
    for (int st = 128; st > 0; st >>= 1) {
        if (tid < st) red[tid] += red[tid+st];
        __syncthreads();
    }
    if (tid == 0) cn[e] = sqrtf(red[0]);
}

// ---------------------------------------------------------------------------
// Router: scores, mask, k_per_token. One block per token.
// ---------------------------------------------------------------------------
__global__ __launch_bounds__(256) void scores_kernel(const float* __restrict__ h2,
                                                     const float* __restrict__ sim,
                                                     const float* __restrict__ cn,
                                                     const float* __restrict__ thr,
                                                     float* __restrict__ scores,
                                                     float* __restrict__ kpt,
                                                     float* __restrict__ maskb) {
    const int row = blockIdx.x, tid = threadIdx.x;
    __shared__ float red[256*17];
    float acc[17] = {};                 // 16 dots + |x|^2 in [16]
    for (int c = tid; c < CC; c += 256) {
        const float xv = h2[(long)row*CC + c];
        acc[16] += xv*xv;
        const float* sr = sim + (long)c*EE;
        #pragma unroll
        for (int e2 = 0; e2 < EE; e2++) acc[e2] += xv*sr[e2];
    }
    #pragma unroll
    for (int e2 = 0; e2 < 17; e2++) red[tid*17 + e2] = acc[e2];
    __syncthreads();
    for (int st = 128; st > 0; st >>= 1) {
        if (tid < st)
            for (int e2 = 0; e2 < 17; e2++) red[tid*17+e2] += red[(tid+st)*17+e2];
        __syncthreads();
    }
    if (tid < EE) {
        const float nrm = sqrtf(red[16]);
        const float sc  = red[tid] / (nrm * cn[tid]);
        scores[(long)row*EE + tid] = sc;
        const float mkv = sc > thr[0] ? 1.f : 0.f;
        maskb[(long)row*EE + tid] = mkv;
        red[tid] = mkv;
    }
    __syncthreads();
    if (tid == 0) {
        float c2 = 0.f;
        for (int e2 = 0; e2 < EE; e2++) c2 += red[e2];
        kpt[row] = c2;
    }
}

// ---------------------------------------------------------------------------
// final[n,c] = sum_e eo[n,e,c] (already masked); x_out += final, in place
// ---------------------------------------------------------------------------
__global__ __launch_bounds__(256) void moe_sum_kernel(const float* __restrict__ eo,
                                                      float* __restrict__ xio) {
    const int row = blockIdx.x, tid = threadIdx.x;
    for (int c = tid; c < CC; c += 256) {
        float s = 0.f;
        #pragma unroll
        for (int e2 = 0; e2 < EE; e2++)
            s += eo[((long)row*EE + e2)*CC + c];
        xio[(long)row*CC + c] += s;
    }
}

// ---------------------------------------------------------------------------
extern "C" void kernel_launch(void* const* d_in, const int* in_sizes, int n_in,
                              void* d_out, int out_size, void* d_ws, size_t ws_size,
                              hipStream_t stream) {
    const float* x     = (const float*)d_in[0];
    const float* ln1_g = (const float*)d_in[1];
    const float* ln1_b = (const float*)d_in[2];
    const float* ln2_g = (const float*)d_in[3];
    const float* ln2_b = (const float*)d_in[4];
    const float* wq    = (const float*)d_in[5];
    const float* wk    = (const float*)d_in[6];
    const float* wv    = (const float*)d_in[7];
    const float* wo    = (const float*)d_in[8];
    const float* sim   = (const float*)d_in[9];
    const float* thr   = (const float*)d_in[10];
    const float* w1    = (const float*)d_in[11];
    const float* w2    = (const float*)d_in[12];

    // d_out layout: x[2M] | scores[32K] | expert_outputs_full[33.5M] | k_per_token[2K]
    float* out_x      = (float*)d_out;
    float* out_scores = out_x + (long)NN*CC;
    float* out_eo     = out_scores + (long)NN*EE;
    float* out_kpt    = out_eo + (long)NN*EE*CC;

    float* ws   = (float*)d_ws;
    float* h    = ws;                          // 2M floats
    float* qb   = ws + 1L*NN*CC;
    float* kb   = ws + 2L*NN*CC;
    float* vb   = ws + 3L*NN*CC;
    float* ao   = ws + 4L*NN*CC;
    float* h2   = ws + 5L*NN*CC;
    float* mid  = ws + 6L*NN*CC;               // E*N*I = 8M floats
    float* maskb = mid + (long)EE*NN*II;       // 32K
    float* cn    = maskb + (long)NN*EE;        // 16

    // 1. LN1
    ln_kernel<<<NN, 256, 0, stream>>>(x, ln1_g, ln1_b, h);

    // 2. QKV projections
    dim3 gqkv(CC/64, NN/64, 1);
    gemm64<0><<<gqkv, 256, 0, stream>>>(h, 0, wq, 0, qb, 0, CC, NN, CC, CC, nullptr, nullptr, EE);
    gemm64<0><<<gqkv, 256, 0, stream>>>(h, 0, wk, 0, kb, 0, CC, NN, CC, CC, nullptr, nullptr, EE);
    gemm64<0><<<gqkv, 256, 0, stream>>>(h, 0, wv, 0, vb, 0, CC, NN, CC, CC, nullptr, nullptr, EE);

    // 3. causal attention (flash-style tiles)
    dim3 gattn(TT/64, HH, BB);
    attn_flash<<<gattn, 256, 0, stream>>>(qb, kb, vb, ao);

    // 4. output projection + residual -> d_out x slot
    gemm64<1><<<gqkv, 256, 0, stream>>>(ao, 0, wo, 0, out_x, 0, CC, NN, CC, CC, x, nullptr, EE);

    // 5. LN2
    ln_kernel<<<NN, 256, 0, stream>>>(out_x, ln2_g, ln2_b, h2);

    // 6. router
    colnorm_kernel<<<EE, 256, 0, stream>>>(sim, cn);
    scores_kernel<<<NN, 256, 0, stream>>>(h2, sim, cn, thr, out_scores, out_kpt, maskb);

    // 7. expert GEMM 1: mid[e] = gelu(h2 @ w1[e])   [N x I per expert]
    dim3 gw1(II/64, NN/64, EE);
    gemm64<2><<<gw1, 256, 0, stream>>>(h2, 0, w1, (long)CC*II, mid, (long)NN*II, II,
                                       NN, II, CC, nullptr, nullptr, EE);

    // 8. expert GEMM 2: eo[n,e,:] = (mid[e] @ w2[e]) * mask[n,e]  (strided into d_out)
    dim3 gw2(CC/64, NN/64, EE);
    gemm64<3><<<gw2, 256, 0, stream>>>(mid, (long)NN*II, w2, (long)II*CC, out_eo, (long)CC, EE*CC,
                                       NN, CC, II, nullptr, maskb, EE);

    // 9. final = sum_e eo; x += final (in place on d_out)
    moe_sum_kernel<<<NN, 256, 0, stream>>>(out_eo, out_x);
}

// Round 3
// 1015.326 us; speedup vs baseline: 1.9690x; 1.3389x over previous
//
#include <hip/hip_runtime.h>
#include <hip/hip_bf16.h>
#include <math.h>

// Problem constants
#define BB 2
#define TT 1024
#define CC 1024
#define HH 16
#define DD 64
#define EE 16
#define II 256
#define NN (BB*TT)          // 2048 tokens
#define EPSLN 1e-5f
#define PADL 68             // fp32 LDS row stride for attn

typedef __attribute__((ext_vector_type(8))) short short8;
typedef __attribute__((ext_vector_type(4))) float f32x4;

// ---------------------------------------------------------------------------
// LayerNorm: one block per row of 1024. Optional bf16 secondary output.
// ---------------------------------------------------------------------------
__global__ __launch_bounds__(256) void ln_kernel(const float* __restrict__ x,
                                                 const float* __restrict__ g,
                                                 const float* __restrict__ bta,
                                                 float* __restrict__ out,
                                                 __hip_bfloat16* __restrict__ outb) {
    const int row = blockIdx.x, tid = threadIdx.x;
    __shared__ float r1[256], r2[256];
    const float* xr = x + (long)row * CC;
    float4 xv = ((const float4*)xr)[tid];
    float s  = xv.x + xv.y + xv.z + xv.w;
    float q2 = xv.x*xv.x + xv.y*xv.y + xv.z*xv.z + xv.w*xv.w;
    r1[tid] = s; r2[tid] = q2; __syncthreads();
    for (int st = 128; st > 0; st >>= 1) {
        if (tid < st) { r1[tid] += r1[tid+st]; r2[tid] += r2[tid+st]; }
        __syncthreads();
    }
    const float mu  = r1[0] * (1.f/CC);
    const float var = r2[0] * (1.f/CC) - mu*mu;
    const float rs  = rsqrtf(var + EPSLN);
    float4 gv = ((const float4*)g)[tid];
    float4 bv = ((const float4*)bta)[tid];
    float4 ov;
    ov.x = (xv.x-mu)*rs*gv.x + bv.x;
    ov.y = (xv.y-mu)*rs*gv.y + bv.y;
    ov.z = (xv.z-mu)*rs*gv.z + bv.z;
    ov.w = (xv.w-mu)*rs*gv.w + bv.w;
    ((float4*)(out + (long)row * CC))[tid] = ov;
    if (outb) {
        __hip_bfloat16* p = outb + (long)row * CC + tid*4;
        p[0] = __float2bfloat16(ov.x); p[1] = __float2bfloat16(ov.y);
        p[2] = __float2bfloat16(ov.z); p[3] = __float2bfloat16(ov.w);
    }
}

// ---------------------------------------------------------------------------
// Tiled fp32 -> bf16 transpose: W [K][N] -> Wt [N][K], batched over experts.
// ---------------------------------------------------------------------------
__global__ __launch_bounds__(256) void transpose_f2b(const float* __restrict__ W, long sWe,
                                                     __hip_bfloat16* __restrict__ Wt, long sWte,
                                                     int K, int N) {
    const int e = blockIdx.z;
    W  += (long)e * sWe;
    Wt += (long)e * sWte;
    const int n0 = blockIdx.x * 32, k0 = blockIdx.y * 32;
    __shared__ float t[32][33];
    const int tx = threadIdx.x & 31, ty = threadIdx.x >> 5;   // ty 0..7
    #pragma unroll
    for (int i = 0; i < 4; i++)
        t[ty + i*8][tx] = W[(long)(k0 + ty + i*8)*N + n0 + tx];
    __syncthreads();
    #pragma unroll
    for (int i = 0; i < 4; i++)
        Wt[(long)(n0 + ty + i*8)*K + k0 + tx] = __float2bfloat16(t[tx][ty + i*8]);
}

// ---------------------------------------------------------------------------
// bf16 MFMA GEMM: C[M,N] = A[M,K] * Bt[N,K]^T, batched over blockIdx.z.
// 128x128 tile, BK=32, 256 threads = 4 waves, each wave 64x64 via 4x4
// mfma_f32_16x16x32_bf16 tiles. LDS row stride 40 bf16 (2-way max aliasing).
// EPI: 0 = exact gelu -> bf16 out; 1 = *mask -> fp32 strided out
// ---------------------------------------------------------------------------
template<int EPI>
__global__ __launch_bounds__(256) void gemm_mfma(
        const __hip_bfloat16* __restrict__ A, long sAe,
        const __hip_bfloat16* __restrict__ Bt, long sBe,
        void* __restrict__ Cp, long sCe, int ldc,
        int M, int N, int K,
        const float* __restrict__ mask) {
    constexpr int LDK = 40;
    __shared__ __hip_bfloat16 As[128][LDK];
    __shared__ __hip_bfloat16 Bs[128][LDK];
    const int e = blockIdx.z;
    A  += (long)e * sAe;
    Bt += (long)e * sBe;
    const int n0 = blockIdx.x * 128, m0 = blockIdx.y * 128;
    const int tid = threadIdx.x;
    const int wave = tid >> 6, lane = tid & 63;
    const int wm = (wave >> 1) * 64, wn = (wave & 1) * 64;
    const int l15 = lane & 15, quad = lane >> 4;

    f32x4 acc[4][4] = {};

    for (int k0 = 0; k0 < K; k0 += 32) {
        #pragma unroll
        for (int it = 0; it < 2; it++) {
            int idx = tid + it*256;           // 0..511
            int r = idx >> 2, kg = idx & 3;   // 128 rows x 4 groups of 8 k
            short8 av = *(const short8*)(A  + (long)(m0 + r)*K + k0 + kg*8);
            short8 bv = *(const short8*)(Bt + (long)(n0 + r)*K + k0 + kg*8);
            *(short8*)&As[r][kg*8] = av;
            *(short8*)&Bs[r][kg*8] = bv;
        }
        __syncthreads();
        short8 af[4], bff[4];
        #pragma unroll
        for (int i = 0; i < 4; i++) {
            af[i]  = *(const short8*)&As[wm + i*16 + l15][quad*8];
            bff[i] = *(const short8*)&Bs[wn + i*16 + l15][quad*8];
        }
        #pragma unroll
        for (int mi = 0; mi < 4; mi++)
            #pragma unroll
            for (int ni = 0; ni < 4; ni++)
                acc[mi][ni] = __builtin_amdgcn_mfma_f32_16x16x32_bf16(
                                  af[mi], bff[ni], acc[mi][ni], 0, 0, 0);
        __syncthreads();
    }

    // epilogue: C/D layout col = lane&15, row = quad*4 + reg (m89/m91-verified)
    #pragma unroll
    for (int mi = 0; mi < 4; mi++) {
        #pragma unroll
        for (int r = 0; r < 4; r++) {
            const int row = m0 + wm + mi*16 + quad*4 + r;
            float mv = 0.f;
            if (EPI == 1) mv = mask[(long)row*EE + e];
            #pragma unroll
            for (int ni = 0; ni < 4; ni++) {
                const int col = n0 + wn + ni*16 + l15;
                float val = acc[mi][ni][r];
                if (EPI == 0) {
                    val = 0.5f*val*(1.f + erff(val*0.70710678118f));
                    ((__hip_bfloat16*)Cp)[(long)e*sCe + (long)row*ldc + col] =
                        __float2bfloat16(val);
                } else {
                    ((float*)Cp)[(long)e*sCe + (long)row*ldc + col] = val*mv;
                }
            }
        }
    }
}

// ---------------------------------------------------------------------------
// fp32 tiled GEMM (attention path only now), 64x64 tile.
// EPI: 0 = plain, 1 = +resid
// ---------------------------------------------------------------------------
template<int EPI>
__global__ __launch_bounds__(256) void gemm64(
        const float* __restrict__ A,
        const float* __restrict__ B,
        float* __restrict__ Cp,
        int M, int N, int K,
        const float* __restrict__ resid) {
    const int n0 = blockIdx.x * 64, m0 = blockIdx.y * 64;
    const int tid = threadIdx.x, tx = tid & 15, ty = tid >> 4;
    __shared__ float As[16][65];
    __shared__ float Bs[16][64];
    float acc[4][4] = {};
    for (int k0 = 0; k0 < K; k0 += 16) {
        #pragma unroll
        for (int i = 0; i < 4; i++) {
            int lin = tid + i*256;
            int mm = lin >> 4, kk = lin & 15;
            As[kk][mm] = A[(long)(m0+mm)*K + k0 + kk];
            int nn = lin & 63, kb = lin >> 6;
            Bs[kb][nn] = B[(long)(k0+kb)*N + n0 + nn];
        }
        __syncthreads();
        #pragma unroll
        for (int kk = 0; kk < 16; kk++) {
            float a[4], bb[4];
            #pragma unroll
            for (int i = 0; i < 4; i++) a[i] = As[kk][ty*4+i];
            #pragma unroll
            for (int j = 0; j < 4; j++) bb[j] = Bs[kk][tx*4+j];
            #pragma unroll
            for (int i = 0; i < 4; i++)
                #pragma unroll
                for (int j = 0; j < 4; j++)
                    acc[i][j] += a[i]*bb[j];
        }
        __syncthreads();
    }
    #pragma unroll
    for (int i = 0; i < 4; i++) {
        const int row = m0 + ty*4 + i;
        #pragma unroll
        for (int j = 0; j < 4; j++) {
            const int col = n0 + tx*4 + j;
            float val = acc[i][j];
            if (EPI == 1) val += resid[(long)row*N + col];
            Cp[(long)row*N + col] = val;
        }
    }
}

// ---------------------------------------------------------------------------
// Flash-style causal attention (fp32). One block per (b, h, 64-row q tile).
// ---------------------------------------------------------------------------
__global__ __launch_bounds__(256) void attn_flash(const float* __restrict__ q,
                                                  const float* __restrict__ k,
                                                  const float* __restrict__ v,
                                                  float* __restrict__ o) {
    __shared__ __align__(16) float Qs[DD][PADL];
    __shared__ __align__(16) float Ks[DD][PADL];
    __shared__ __align__(16) float Vs[64][PADL];
    __shared__ __align__(16) float Ps[64][PADL];
    __shared__ float mrow[64], lrow[64], arow[64];

    const int qt = blockIdx.x, h = blockIdx.y, b = blockIdx.z;
    const int tid = threadIdx.x;
    const long base = (long)b * TT * CC + (long)h * DD;

    #pragma unroll
    for (int i = 0; i < 16; i++) {
        int lin = tid + i*256;
        int r = lin >> 6, c = lin & 63;
        Qs[c][r] = q[base + (long)(qt*64 + r)*CC + c];
    }
    if (tid < 64) { mrow[tid] = -1e30f; lrow[tid] = 0.f; }

    const int g4 = tid >> 4;
    const int l4 = tid & 15;
    const int r0 = g4 * 4;
    const int c0 = l4 * 4;

    float acc[4][4] = {{0.f}};

    for (int kt = 0; kt <= qt; kt++) {
        __syncthreads();
        #pragma unroll
        for (int i = 0; i < 16; i++) {
            int lin = tid + i*256;
            int r = lin >> 6, c = lin & 63;
            Ks[c][r] = k[base + (long)(kt*64 + r)*CC + c];
            Vs[r][c] = v[base + (long)(kt*64 + r)*CC + c];
        }
        __syncthreads();

        float s00=0,s01=0,s02=0,s03=0, s10=0,s11=0,s12=0,s13=0;
        float s20=0,s21=0,s22=0,s23=0, s30=0,s31=0,s32=0,s33=0;
        #pragma unroll 8
        for (int d = 0; d < DD; d++) {
            float4 a  = *(const float4*)&Qs[d][r0];
            float4 bv = *(const float4*)&Ks[d][c0];
            s00 += a.x*bv.x; s01 += a.x*bv.y; s02 += a.x*bv.z; s03 += a.x*bv.w;
            s10 += a.y*bv.x; s11 += a.y*bv.y; s12 += a.y*bv.z; s13 += a.y*bv.w;
            s20 += a.z*bv.x; s21 += a.z*bv.y; s22 += a.z*bv.z; s23 += a.z*bv.w;
            s30 += a.w*bv.x; s31 += a.w*bv.y; s32 += a.w*bv.z; s33 += a.w*bv.w;
        }
        float sarr[4][4] = {{s00,s01,s02,s03},{s10,s11,s12,s13},
                            {s20,s21,s22,s23},{s30,s31,s32,s33}};
        const bool diag = (kt == qt);
        #pragma unroll
        for (int j = 0; j < 4; j++)
            #pragma unroll
            for (int i = 0; i < 4; i++) {
                int rr = r0 + i, kk = c0 + j;
                float val = sarr[i][j] * 0.125f;
                if (diag && kk > rr) val = -1e30f;
                Ps[kk][rr] = val;
            }
        __syncthreads();

        if (tid < 64) {
            const int rr = tid;
            const float mo = mrow[rr];
            float mx = mo;
            #pragma unroll 8
            for (int kk = 0; kk < 64; kk++) mx = fmaxf(mx, Ps[kk][rr]);
            const float al = __expf(mo - mx);
            float rs = 0.f;
            #pragma unroll 8
            for (int kk = 0; kk < 64; kk++) {
                float p = __expf(Ps[kk][rr] - mx);
                Ps[kk][rr] = p;
                rs += p;
            }
            mrow[rr] = mx;
            lrow[rr] = lrow[rr] * al + rs;
            arow[rr] = al;
        }
        __syncthreads();

        const float al0 = arow[r0], al1 = arow[r0+1], al2 = arow[r0+2], al3 = arow[r0+3];
        #pragma unroll
        for (int j = 0; j < 4; j++) {
            acc[0][j] *= al0; acc[1][j] *= al1; acc[2][j] *= al2; acc[3][j] *= al3;
        }
        #pragma unroll 8
        for (int kk = 0; kk < 64; kk++) {
            float4 p  = *(const float4*)&Ps[kk][r0];
            float4 vv = *(const float4*)&Vs[kk][c0];
            acc[0][0] += p.x*vv.x; acc[0][1] += p.x*vv.y; acc[0][2] += p.x*vv.z; acc[0][3] += p.x*vv.w;
            acc[1][0] += p.y*vv.x; acc[1][1] += p.y*vv.y; acc[1][2] += p.y*vv.z; acc[1][3] += p.y*vv.w;
            acc[2][0] += p.z*vv.x; acc[2][1] += p.z*vv.y; acc[2][2] += p.z*vv.z; acc[2][3] += p.z*vv.w;
            acc[3][0] += p.w*vv.x; acc[3][1] += p.w*vv.y; acc[3][2] += p.w*vv.z; acc[3][3] += p.w*vv.w;
        }
    }

    const float i0 = 1.f/lrow[r0], i1 = 1.f/lrow[r0+1], i2 = 1.f/lrow[r0+2], i3 = 1.f/lrow[r0+3];
    const float invs[4] = {i0, i1, i2, i3};
    #pragma unroll
    for (int i = 0; i < 4; i++) {
        float4 ov;
        ov.x = acc[i][0]*invs[i]; ov.y = acc[i][1]*invs[i];
        ov.z = acc[i][2]*invs[i]; ov.w = acc[i][3]*invs[i];
        *(float4*)&o[base + (long)(qt*64 + r0 + i)*CC + c0] = ov;
    }
}

// ---------------------------------------------------------------------------
// Column norms of sim_matrix [C, E]
// ---------------------------------------------------------------------------
__global__ __launch_bounds__(256) void colnorm_kernel(const float* __restrict__ sim,
                                                      float* __restrict__ cn) {
    const int e = blockIdx.x, tid = threadIdx.x;
    __shared__ float red[256];
    float s = 0.f;
    for (int c = tid; c < CC; c += 256) {
        float vv = sim[(long)c*EE + e];
        s += vv*vv;
    }
    red[tid] = s; __syncthreads();
    for (int st = 128; st > 0; st >>= 1) {
        if (tid < st) red[tid] += red[tid+st];
        __syncthreads();
    }
    if (tid == 0) cn[e] = sqrtf(red[0]);
}

// ---------------------------------------------------------------------------
// Router: scores, mask, k_per_token (fp32-exact). One block per token.
// ---------------------------------------------------------------------------
__global__ __launch_bounds__(256) void scores_kernel(const float* __restrict__ h2,
                                                     const float* __restrict__ sim,
                                                     const float* __restrict__ cn,
                                                     const float* __restrict__ thr,
                                                     float* __restrict__ scores,
                                                     float* __restrict__ kpt,
                                                     float* __restrict__ maskb) {
    const int row = blockIdx.x, tid = threadIdx.x;
    __shared__ float red[256*17];
    float acc[17] = {};
    for (int c = tid; c < CC; c += 256) {
        const float xv = h2[(long)row*CC + c];
        acc[16] += xv*xv;
        const float* sr = sim + (long)c*EE;
        #pragma unroll
        for (int e2 = 0; e2 < EE; e2++) acc[e2] += xv*sr[e2];
    }
    #pragma unroll
    for (int e2 = 0; e2 < 17; e2++) red[tid*17 + e2] = acc[e2];
    __syncthreads();
    for (int st = 128; st > 0; st >>= 1) {
        if (tid < st)
            for (int e2 = 0; e2 < 17; e2++) red[tid*17+e2] += red[(tid+st)*17+e2];
        __syncthreads();
    }
    if (tid < EE) {
        const float nrm = sqrtf(red[16]);
        const float sc  = red[tid] / (nrm * cn[tid]);
        scores[(long)row*EE + tid] = sc;
        const float mkv = sc > thr[0] ? 1.f : 0.f;
        maskb[(long)row*EE + tid] = mkv;
        red[tid] = mkv;
    }
    __syncthreads();
    if (tid == 0) {
        float c2 = 0.f;
        for (int e2 = 0; e2 < EE; e2++) c2 += red[e2];
        kpt[row] = c2;
    }
}

// ---------------------------------------------------------------------------
// final[n,c] = sum_e eo[n,e,c]; x_out += final, in place
// ---------------------------------------------------------------------------
__global__ __launch_bounds__(256) void moe_sum_kernel(const float* __restrict__ eo,
                                                      float* __restrict__ xio) {
    const int row = blockIdx.x, tid = threadIdx.x;
    for (int c = tid; c < CC; c += 256) {
        float s = 0.f;
        #pragma unroll
        for (int e2 = 0; e2 < EE; e2++)
            s += eo[((long)row*EE + e2)*CC + c];
        xio[(long)row*CC + c] += s;
    }
}

// ---------------------------------------------------------------------------
extern "C" void kernel_launch(void* const* d_in, const int* in_sizes, int n_in,
                              void* d_out, int out_size, void* d_ws, size_t ws_size,
                              hipStream_t stream) {
    const float* x     = (const float*)d_in[0];
    const float* ln1_g = (const float*)d_in[1];
    const float* ln1_b = (const float*)d_in[2];
    const float* ln2_g = (const float*)d_in[3];
    const float* ln2_b = (const float*)d_in[4];
    const float* wq    = (const float*)d_in[5];
    const float* wk    = (const float*)d_in[6];
    const float* wv    = (const float*)d_in[7];
    const float* wo    = (const float*)d_in[8];
    const float* sim   = (const float*)d_in[9];
    const float* thr   = (const float*)d_in[10];
    const float* w1    = (const float*)d_in[11];
    const float* w2    = (const float*)d_in[12];

    float* out_x      = (float*)d_out;
    float* out_scores = out_x + (long)NN*CC;
    float* out_eo     = out_scores + (long)NN*EE;
    float* out_kpt    = out_eo + (long)NN*EE*CC;

    const long MF = (long)NN*CC;     // 2M floats
    float* ws   = (float*)d_ws;
    float* h    = ws;                // LN1 out; reused as h2 fp32 after WO
    float* qb   = ws + MF;
    float* kb   = ws + 2*MF;
    float* vb   = ws + 3*MF;
    float* ao   = ws + 4*MF;
    __hip_bfloat16* h2b = (__hip_bfloat16*)(ws + 5*MF);              // 2M elems
    __hip_bfloat16* mid = (__hip_bfloat16*)(ws + 5*MF + MF/2);       // 8M elems
    __hip_bfloat16* w1t = (__hip_bfloat16*)(ws + 7*MF + MF/2);       // 4M elems
    __hip_bfloat16* w2t = (__hip_bfloat16*)(ws + 8*MF + MF/2);       // 4M elems
    float* maskb = ws + 9*MF + MF/2;                                  // 32K
    float* cn    = maskb + (long)NN*EE;                               // 16

    // 0. weight transposes (fp32 -> bf16, [K][N] -> [N][K]) for expert GEMMs
    {
        dim3 g1(II/32, CC/32, EE);   // w1 [E][C][I] -> w1t [E][I][C]
        transpose_f2b<<<g1, 256, 0, stream>>>(w1, (long)CC*II, w1t, (long)CC*II, CC, II);
        dim3 g2(CC/32, II/32, EE);   // w2 [E][I][C] -> w2t [E][C][I]
        transpose_f2b<<<g2, 256, 0, stream>>>(w2, (long)II*CC, w2t, (long)II*CC, II, CC);
    }

    // 1. LN1 (fp32 only — attention path stays fp32 for router exactness)
    ln_kernel<<<NN, 256, 0, stream>>>(x, ln1_g, ln1_b, h, nullptr);

    // 2. QKV projections (fp32)
    dim3 gqkv(CC/64, NN/64, 1);
    gemm64<0><<<gqkv, 256, 0, stream>>>(h, wq, qb, NN, CC, CC, nullptr);
    gemm64<0><<<gqkv, 256, 0, stream>>>(h, wk, kb, NN, CC, CC, nullptr);
    gemm64<0><<<gqkv, 256, 0, stream>>>(h, wv, vb, NN, CC, CC, nullptr);

    // 3. causal attention (flash-style tiles, fp32)
    dim3 gattn(TT/64, HH, BB);
    attn_flash<<<gattn, 256, 0, stream>>>(qb, kb, vb, ao);

    // 4. output projection + residual -> d_out x slot
    gemm64<1><<<gqkv, 256, 0, stream>>>(ao, wo, out_x, NN, CC, CC, x);

    // 5. LN2 -> h (fp32 for router) + h2b (bf16 for expert GEMM)
    ln_kernel<<<NN, 256, 0, stream>>>(out_x, ln2_g, ln2_b, h, h2b);

    // 6. router (fp32-exact so mask matches reference bit-stably)
    colnorm_kernel<<<EE, 256, 0, stream>>>(sim, cn);
    scores_kernel<<<NN, 256, 0, stream>>>(h, sim, cn, thr, out_scores, out_kpt, maskb);

    // 7. expert GEMM 1 (MFMA bf16): mid[e] = gelu(h2 @ w1[e]) -> bf16
    {
        dim3 g(II/128, NN/128, EE);
        gemm_mfma<0><<<g, 256, 0, stream>>>(h2b, 0, w1t, (long)II*CC,
                                            mid, (long)NN*II, II,
                                            NN, II, CC, nullptr);
    }

    // 8. expert GEMM 2 (MFMA bf16): eo[n,e,:] = (mid[e] @ w2[e]) * mask[n,e]
    {
        dim3 g(CC/128, NN/128, EE);
        gemm_mfma<1><<<g, 256, 0, stream>>>(mid, (long)NN*II, w2t, (long)II*CC,
                                            out_eo, (long)CC, EE*CC,
                                            NN, CC, II, maskb);
    }

    // 9. final = sum_e eo; x += final (in place on d_out)
    moe_sum_kernel<<<NN, 256, 0, stream>>>(out_eo, out_x);
}

// Round 4
// 830.050 us; speedup vs baseline: 2.4085x; 1.2232x over previous
//
#include <hip/hip_runtime.h>
#include <hip/hip_bf16.h>
#include <math.h>

// Problem constants
#define BB 2
#define TT 1024
#define CC 1024
#define HH 16
#define DD 64
#define EE 16
#define II 256
#define NN (BB*TT)          // 2048 tokens
#define EPSLN 1e-5f
#define PADL 68             // fp32 LDS row stride for attn

typedef __attribute__((ext_vector_type(8))) short short8;
typedef __attribute__((ext_vector_type(4))) float f32x4;

__device__ inline void splitbf(float x, short& hi, short& lo) {
    __hip_bfloat16 h = __float2bfloat16(x);
    float hf = __bfloat162float(h);
    __hip_bfloat16 l = __float2bfloat16(x - hf);
    hi = *(short*)&h;
    lo = *(short*)&l;
}

// ---------------------------------------------------------------------------
// LayerNorm: one block per row of 1024. Optional bf16 secondary output.
// ---------------------------------------------------------------------------
__global__ __launch_bounds__(256) void ln_kernel(const float* __restrict__ x,
                                                 const float* __restrict__ g,
                                                 const float* __restrict__ bta,
                                                 float* __restrict__ out,
                                                 __hip_bfloat16* __restrict__ outb) {
    const int row = blockIdx.x, tid = threadIdx.x;
    __shared__ float r1[256], r2[256];
    const float* xr = x + (long)row * CC;
    float4 xv = ((const float4*)xr)[tid];
    float s  = xv.x + xv.y + xv.z + xv.w;
    float q2 = xv.x*xv.x + xv.y*xv.y + xv.z*xv.z + xv.w*xv.w;
    r1[tid] = s; r2[tid] = q2; __syncthreads();
    for (int st = 128; st > 0; st >>= 1) {
        if (tid < st) { r1[tid] += r1[tid+st]; r2[tid] += r2[tid+st]; }
        __syncthreads();
    }
    const float mu  = r1[0] * (1.f/CC);
    const float var = r2[0] * (1.f/CC) - mu*mu;
    const float rs  = rsqrtf(var + EPSLN);
    float4 gv = ((const float4*)g)[tid];
    float4 bv = ((const float4*)bta)[tid];
    float4 ov;
    ov.x = (xv.x-mu)*rs*gv.x + bv.x;
    ov.y = (xv.y-mu)*rs*gv.y + bv.y;
    ov.z = (xv.z-mu)*rs*gv.z + bv.z;
    ov.w = (xv.w-mu)*rs*gv.w + bv.w;
    ((float4*)(out + (long)row * CC))[tid] = ov;
    if (outb) {
        __hip_bfloat16* p = outb + (long)row * CC + tid*4;
        p[0] = __float2bfloat16(ov.x); p[1] = __float2bfloat16(ov.y);
        p[2] = __float2bfloat16(ov.z); p[3] = __float2bfloat16(ov.w);
    }
}

// ---------------------------------------------------------------------------
// fp32-accurate MFMA GEMM via bf16x3 split (AhBh + AhBl + AlBh).
// C[M,N] = A[M,K] * W[K,N] (+resid). Tile 64Mx128N, BK=32, 4 waves.
// A fp32 split at stage time; W fp32 transposed+split at stage time.
// EPI: 0 = plain, 1 = +resid
// ---------------------------------------------------------------------------
template<int EPI>
__global__ __launch_bounds__(256, 2) void gemm_mfma32(
        const float* __restrict__ A,
        const float* __restrict__ W,
        float* __restrict__ Cp,
        int M, int N, int K,
        const float* __restrict__ resid) {
    __shared__ __hip_bfloat16 Ash[64][40], Asl[64][40];
    __shared__ __hip_bfloat16 Bsh[128][40], Bsl[128][40];
    const int n0 = blockIdx.x * 128, m0 = blockIdx.y * 64;
    const int tid = threadIdx.x;
    const int wave = tid >> 6, lane = tid & 63;
    const int wm = (wave >> 1) * 32, wn = (wave & 1) * 64;
    const int l15 = lane & 15, quad = lane >> 4;

    f32x4 acc[2][4] = {};

    for (int k0 = 0; k0 < K; k0 += 32) {
        // ---- stage A: 64 rows x 32 k, fp32 -> hi/lo bf16
        {
            const int r = tid >> 2, kg = (tid & 3) * 8;
            const float* ap = A + (long)(m0 + r)*K + k0 + kg;
            float4 x0 = *(const float4*)ap, x1 = *(const float4*)(ap + 4);
            float xs[8] = {x0.x,x0.y,x0.z,x0.w,x1.x,x1.y,x1.z,x1.w};
            short8 hv, lv;
            #pragma unroll
            for (int j = 0; j < 8; j++) { short h,l; splitbf(xs[j], h, l); hv[j]=h; lv[j]=l; }
            *(short8*)&Ash[r][kg] = hv;
            *(short8*)&Asl[r][kg] = lv;
        }
        // ---- stage W transposed: W[k0+kk][n0+n] -> Bs[n][kk], hi/lo
        #pragma unroll
        for (int it = 0; it < 2; it++) {
            const int idx = tid + it*256;         // 0..511
            const int kk = idx >> 4;              // 0..31
            const int n8 = (idx & 15) * 8;        // 0..120
            const float* wp = W + (long)(k0 + kk)*N + n0 + n8;
            float4 x0 = *(const float4*)wp, x1 = *(const float4*)(wp + 4);
            float xs[8] = {x0.x,x0.y,x0.z,x0.w,x1.x,x1.y,x1.z,x1.w};
            #pragma unroll
            for (int j = 0; j < 8; j++) {
                short h,l; splitbf(xs[j], h, l);
                *(short*)&Bsh[n8+j][kk] = h;
                *(short*)&Bsl[n8+j][kk] = l;
            }
        }
        __syncthreads();
        short8 ah[2], al[2], bh[4], bl[4];
        #pragma unroll
        for (int mi = 0; mi < 2; mi++) {
            ah[mi] = *(const short8*)&Ash[wm + mi*16 + l15][quad*8];
            al[mi] = *(const short8*)&Asl[wm + mi*16 + l15][quad*8];
        }
        #pragma unroll
        for (int ni = 0; ni < 4; ni++) {
            bh[ni] = *(const short8*)&Bsh[wn + ni*16 + l15][quad*8];
            bl[ni] = *(const short8*)&Bsl[wn + ni*16 + l15][quad*8];
        }
        #pragma unroll
        for (int mi = 0; mi < 2; mi++)
            #pragma unroll
            for (int ni = 0; ni < 4; ni++) {
                acc[mi][ni] = __builtin_amdgcn_mfma_f32_16x16x32_bf16(ah[mi], bh[ni], acc[mi][ni], 0,0,0);
                acc[mi][ni] = __builtin_amdgcn_mfma_f32_16x16x32_bf16(ah[mi], bl[ni], acc[mi][ni], 0,0,0);
                acc[mi][ni] = __builtin_amdgcn_mfma_f32_16x16x32_bf16(al[mi], bh[ni], acc[mi][ni], 0,0,0);
            }
        __syncthreads();
    }

    #pragma unroll
    for (int mi = 0; mi < 2; mi++)
        #pragma unroll
        for (int r = 0; r < 4; r++) {
            const int row = m0 + wm + mi*16 + quad*4 + r;
            #pragma unroll
            for (int ni = 0; ni < 4; ni++) {
                const int col = n0 + wn + ni*16 + l15;
                float val = acc[mi][ni][r];
                if (EPI == 1) val += resid[(long)row*N + col];
                Cp[(long)row*N + col] = val;
            }
        }
}

// ---------------------------------------------------------------------------
// bf16 MFMA GEMM (expert path): C = A[M,K] * Bt[N,K]^T, batched over z.
// EPI: 0 = exact gelu -> bf16 out; 1 = *mask -> fp32 strided out
// ---------------------------------------------------------------------------
template<int EPI>
__global__ __launch_bounds__(256) void gemm_mfma(
        const __hip_bfloat16* __restrict__ A, long sAe,
        const __hip_bfloat16* __restrict__ Bt, long sBe,
        void* __restrict__ Cp, long sCe, int ldc,
        int M, int N, int K,
        const float* __restrict__ mask) {
    constexpr int LDK = 40;
    __shared__ __hip_bfloat16 As[128][LDK];
    __shared__ __hip_bfloat16 Bs[128][LDK];
    const int e = blockIdx.z;
    A  += (long)e * sAe;
    Bt += (long)e * sBe;
    const int n0 = blockIdx.x * 128, m0 = blockIdx.y * 128;
    const int tid = threadIdx.x;
    const int wave = tid >> 6, lane = tid & 63;
    const int wm = (wave >> 1) * 64, wn = (wave & 1) * 64;
    const int l15 = lane & 15, quad = lane >> 4;

    f32x4 acc[4][4] = {};

    for (int k0 = 0; k0 < K; k0 += 32) {
        #pragma unroll
        for (int it = 0; it < 2; it++) {
            int idx = tid + it*256;
            int r = idx >> 2, kg = idx & 3;
            short8 av = *(const short8*)(A  + (long)(m0 + r)*K + k0 + kg*8);
            short8 bv = *(const short8*)(Bt + (long)(n0 + r)*K + k0 + kg*8);
            *(short8*)&As[r][kg*8] = av;
            *(short8*)&Bs[r][kg*8] = bv;
        }
        __syncthreads();
        short8 af[4], bff[4];
        #pragma unroll
        for (int i = 0; i < 4; i++) {
            af[i]  = *(const short8*)&As[wm + i*16 + l15][quad*8];
            bff[i] = *(const short8*)&Bs[wn + i*16 + l15][quad*8];
        }
        #pragma unroll
        for (int mi = 0; mi < 4; mi++)
            #pragma unroll
            for (int ni = 0; ni < 4; ni++)
                acc[mi][ni] = __builtin_amdgcn_mfma_f32_16x16x32_bf16(
                                  af[mi], bff[ni], acc[mi][ni], 0, 0, 0);
        __syncthreads();
    }

    #pragma unroll
    for (int mi = 0; mi < 4; mi++) {
        #pragma unroll
        for (int r = 0; r < 4; r++) {
            const int row = m0 + wm + mi*16 + quad*4 + r;
            float mv = 0.f;
            if (EPI == 1) mv = mask[(long)row*EE + e];
            #pragma unroll
            for (int ni = 0; ni < 4; ni++) {
                const int col = n0 + wn + ni*16 + l15;
                float val = acc[mi][ni][r];
                if (EPI == 0) {
                    val = 0.5f*val*(1.f + erff(val*0.70710678118f));
                    ((__hip_bfloat16*)Cp)[(long)e*sCe + (long)row*ldc + col] =
                        __float2bfloat16(val);
                } else {
                    ((float*)Cp)[(long)e*sCe + (long)row*ldc + col] = val*mv;
                }
            }
        }
    }
}

// ---------------------------------------------------------------------------
// Tiled fp32 -> bf16 transpose for expert weights.
// ---------------------------------------------------------------------------
__global__ __launch_bounds__(256) void transpose_f2b(const float* __restrict__ W, long sWe,
                                                     __hip_bfloat16* __restrict__ Wt, long sWte,
                                                     int K, int N) {
    const int e = blockIdx.z;
    W  += (long)e * sWe;
    Wt += (long)e * sWte;
    const int n0 = blockIdx.x * 32, k0 = blockIdx.y * 32;
    __shared__ float t[32][33];
    const int tx = threadIdx.x & 31, ty = threadIdx.x >> 5;
    #pragma unroll
    for (int i = 0; i < 4; i++)
        t[ty + i*8][tx] = W[(long)(k0 + ty + i*8)*N + n0 + tx];
    __syncthreads();
    #pragma unroll
    for (int i = 0; i < 4; i++)
        Wt[(long)(n0 + ty + i*8)*K + k0 + tx] = __float2bfloat16(t[tx][ty + i*8]);
}

// ---------------------------------------------------------------------------
// Flash attention, kt-split for balance. Block = (b, h, qt, half-range).
// Ps aliased onto Ks (saves 17KB -> 3 blocks/CU). In-register online
// softmax via width-16 shuffles. Writes unnormalized O + (m,l) partials.
// ---------------------------------------------------------------------------
__global__ __launch_bounds__(256, 3) void attn_split(const float* __restrict__ q,
                                                     const float* __restrict__ k,
                                                     const float* __restrict__ v,
                                                     float* __restrict__ Opart,
                                                     float* __restrict__ mpart,
                                                     float* __restrict__ lpart) {
    __shared__ __align__(16) float Qs[DD][PADL];
    __shared__ __align__(16) float KPs[64][PADL];   // K (transposed) then P
    __shared__ __align__(16) float Vs[64][PADL];

    const int bx = blockIdx.x;                 // 0..31, heavy qt first
    const int qt = 15 - (bx >> 1), half = bx & 1;
    const int h = blockIdx.y, b = blockIdx.z;
    const int tid = threadIdx.x;
    const long base = (long)b * TT * CC + (long)h * DD;
    const int pidx = ((b*HH + h)*16 + qt)*2 + half;
    float* Op = Opart + (long)pidx * 64 * 64;

    const int n_kt = qt + 1, mid_kt = (n_kt + 1) >> 1;
    const int kt_lo = half ? mid_kt : 0;
    const int kt_hi = half ? n_kt   : mid_kt;

    const int g4 = tid >> 4, l4 = tid & 15;
    const int r0 = g4 * 4, c0 = l4 * 4;

    if (kt_lo >= kt_hi) {      // empty half (qt=0): write neutral partials
        for (int i = tid; i < 64*64; i += 256) Op[i] = 0.f;
        if (tid < 64) { mpart[(long)pidx*64 + tid] = -1e30f; lpart[(long)pidx*64 + tid] = 0.f; }
        return;
    }

    #pragma unroll
    for (int i = 0; i < 16; i++) {
        int lin = tid + i*256;
        int r = lin >> 6, c = lin & 63;
        Qs[c][r] = q[base + (long)(qt*64 + r)*CC + c];
    }

    float m_run[4], l_run[4];
    #pragma unroll
    for (int i = 0; i < 4; i++) { m_run[i] = -1e30f; l_run[i] = 0.f; }
    float acc[4][4] = {{0.f}};

    for (int kt = kt_lo; kt < kt_hi; kt++) {
        __syncthreads();     // prior PV reads of KPs/Vs done (covers Qs 1st iter)
        #pragma unroll
        for (int i = 0; i < 16; i++) {
            int lin = tid + i*256;
            int r = lin >> 6, c = lin & 63;
            KPs[c][r] = k[base + (long)(kt*64 + r)*CC + c];
            Vs[r][c]  = v[base + (long)(kt*64 + r)*CC + c];
        }
        __syncthreads();

        // QK: s[i][j] = sum_d Q[r0+i][d] * K[c0+j][d]
        float s00=0,s01=0,s02=0,s03=0, s10=0,s11=0,s12=0,s13=0;
        float s20=0,s21=0,s22=0,s23=0, s30=0,s31=0,s32=0,s33=0;
        #pragma unroll 8
        for (int d = 0; d < DD; d++) {
            float4 a  = *(const float4*)&Qs[d][r0];
            float4 bv = *(const float4*)&KPs[d][c0];
            s00 += a.x*bv.x; s01 += a.x*bv.y; s02 += a.x*bv.z; s03 += a.x*bv.w;
            s10 += a.y*bv.x; s11 += a.y*bv.y; s12 += a.y*bv.z; s13 += a.y*bv.w;
            s20 += a.z*bv.x; s21 += a.z*bv.y; s22 += a.z*bv.z; s23 += a.z*bv.w;
            s30 += a.w*bv.x; s31 += a.w*bv.y; s32 += a.w*bv.z; s33 += a.w*bv.w;
        }
        float sarr[4][4] = {{s00,s01,s02,s03},{s10,s11,s12,s13},
                            {s20,s21,s22,s23},{s30,s31,s32,s33}};
        const bool diag = (kt == qt);
        float alpha[4];
        #pragma unroll
        for (int i = 0; i < 4; i++) {
            #pragma unroll
            for (int j = 0; j < 4; j++) {
                float val = sarr[i][j] * 0.125f;
                if (diag && (c0 + j) > (r0 + i)) val = -1e30f;
                sarr[i][j] = val;
            }
            float mx = fmaxf(fmaxf(sarr[i][0], sarr[i][1]), fmaxf(sarr[i][2], sarr[i][3]));
            #pragma unroll
            for (int off = 1; off < 16; off <<= 1) mx = fmaxf(mx, __shfl_xor(mx, off, 16));
            const float mnew = fmaxf(m_run[i], mx);
            alpha[i] = __expf(m_run[i] - mnew);
            float rsum = 0.f;
            #pragma unroll
            for (int j = 0; j < 4; j++) {
                float p = __expf(sarr[i][j] - mnew);
                sarr[i][j] = p;
                rsum += p;
            }
            #pragma unroll
            for (int off = 1; off < 16; off <<= 1) rsum += __shfl_xor(rsum, off, 16);
            l_run[i] = l_run[i]*alpha[i] + rsum;
            m_run[i] = mnew;
        }
        __syncthreads();     // KPs reads (QK) done -> safe to overwrite as Ps
        #pragma unroll
        for (int j = 0; j < 4; j++)
            #pragma unroll
            for (int i = 0; i < 4; i++)
                KPs[c0 + j][r0 + i] = sarr[i][j];
        __syncthreads();

        #pragma unroll
        for (int j = 0; j < 4; j++) {
            acc[0][j] *= alpha[0]; acc[1][j] *= alpha[1];
            acc[2][j] *= alpha[2]; acc[3][j] *= alpha[3];
        }
        #pragma unroll 8
        for (int kk = 0; kk < 64; kk++) {
            float4 p  = *(const float4*)&KPs[kk][r0];
            float4 vv = *(const float4*)&Vs[kk][c0];
            acc[0][0] += p.x*vv.x; acc[0][1] += p.x*vv.y; acc[0][2] += p.x*vv.z; acc[0][3] += p.x*vv.w;
            acc[1][0] += p.y*vv.x; acc[1][1] += p.y*vv.y; acc[1][2] += p.y*vv.z; acc[1][3] += p.y*vv.w;
            acc[2][0] += p.z*vv.x; acc[2][1] += p.z*vv.y; acc[2][2] += p.z*vv.z; acc[2][3] += p.z*vv.w;
            acc[3][0] += p.w*vv.x; acc[3][1] += p.w*vv.y; acc[3][2] += p.w*vv.z; acc[3][3] += p.w*vv.w;
        }
    }

    #pragma unroll
    for (int i = 0; i < 4; i++)
        #pragma unroll
        for (int j = 0; j < 4; j++)
            Op[(r0 + i)*64 + c0 + j] = acc[i][j];
    if (l4 == 0) {
        #pragma unroll
        for (int i = 0; i < 4; i++) {
            mpart[(long)pidx*64 + r0 + i] = m_run[i];
            lpart[(long)pidx*64 + r0 + i] = l_run[i];
        }
    }
}

// ---------------------------------------------------------------------------
// Merge the two kt-half partials -> normalized attention output.
// ---------------------------------------------------------------------------
__global__ __launch_bounds__(256) void attn_merge(const float* __restrict__ Opart,
                                                  const float* __restrict__ mpart,
                                                  const float* __restrict__ lpart,
                                                  float* __restrict__ ao) {
    const int qt = blockIdx.x, h = blockIdx.y, b = blockIdx.z;
    const int pA = ((b*HH + h)*16 + qt)*2, pB = pA + 1;
    const int tid = threadIdx.x;
    const int r = tid >> 2, c0 = (tid & 3) * 16;
    const float mA = mpart[(long)pA*64 + r], mB = mpart[(long)pB*64 + r];
    const float lA = lpart[(long)pA*64 + r], lB = lpart[(long)pB*64 + r];
    const float M  = fmaxf(mA, mB);
    const float wA = __expf(mA - M), wB = __expf(mB - M);
    const float inv = 1.f / (lA*wA + lB*wB);
    const float* OA = Opart + (long)pA*4096 + r*64 + c0;
    const float* OB = Opart + (long)pB*4096 + r*64 + c0;
    float* dst = ao + (long)b*TT*CC + (long)(qt*64 + r)*CC + h*DD + c0;
    #pragma unroll
    for (int j = 0; j < 16; j += 4) {
        float4 oa = *(const float4*)(OA + j);
        float4 ob = *(const float4*)(OB + j);
        float4 o;
        o.x = (oa.x*wA + ob.x*wB)*inv; o.y = (oa.y*wA + ob.y*wB)*inv;
        o.z = (oa.z*wA + ob.z*wB)*inv; o.w = (oa.w*wA + ob.w*wB)*inv;
        *(float4*)(dst + j) = o;
    }
}

// ---------------------------------------------------------------------------
// Column norms of sim_matrix [C, E]
// ---------------------------------------------------------------------------
__global__ __launch_bounds__(256) void colnorm_kernel(const float* __restrict__ sim,
                                                      float* __restrict__ cn) {
    const int e = blockIdx.x, tid = threadIdx.x;
    __shared__ float red[256];
    float s = 0.f;
    for (int c = tid; c < CC; c += 256) {
        float vv = sim[(long)c*EE + e];
        s += vv*vv;
    }
    red[tid] = s; __syncthreads();
    for (int st = 128; st > 0; st >>= 1) {
        if (tid < st) red[tid] += red[tid+st];
        __syncthreads();
    }
    if (tid == 0) cn[e] = sqrtf(red[0]);
}

// ---------------------------------------------------------------------------
// Router: scores, mask, k_per_token (fp32-exact). One block per token.
// ---------------------------------------------------------------------------
__global__ __launch_bounds__(256) void scores_kernel(const float* __restrict__ h2,
                                                     const float* __restrict__ sim,
                                                     const float* __restrict__ cn,
                                                     const float* __restrict__ thr,
                                                     float* __restrict__ scores,
                                                     float* __restrict__ kpt,
                                                     float* __restrict__ maskb) {
    const int row = blockIdx.x, tid = threadIdx.x;
    __shared__ float red[256*17];
    float acc[17] = {};
    for (int c = tid; c < CC; c += 256) {
        const float xv = h2[(long)row*CC + c];
        acc[16] += xv*xv;
        const float* sr = sim + (long)c*EE;
        #pragma unroll
        for (int e2 = 0; e2 < EE; e2++) acc[e2] += xv*sr[e2];
    }
    #pragma unroll
    for (int e2 = 0; e2 < 17; e2++) red[tid*17 + e2] = acc[e2];
    __syncthreads();
    for (int st = 128; st > 0; st >>= 1) {
        if (tid < st)
            for (int e2 = 0; e2 < 17; e2++) red[tid*17+e2] += red[(tid+st)*17+e2];
        __syncthreads();
    }
    if (tid < EE) {
        const float nrm = sqrtf(red[16]);
        const float sc  = red[tid] / (nrm * cn[tid]);
        scores[(long)row*EE + tid] = sc;
        const float mkv = sc > thr[0] ? 1.f : 0.f;
        maskb[(long)row*EE + tid] = mkv;
        red[tid] = mkv;
    }
    __syncthreads();
    if (tid == 0) {
        float c2 = 0.f;
        for (int e2 = 0; e2 < EE; e2++) c2 += red[e2];
        kpt[row] = c2;
    }
}

// ---------------------------------------------------------------------------
// final[n,c] = sum_e eo[n,e,c]; x_out += final, in place
// ---------------------------------------------------------------------------
__global__ __launch_bounds__(256) void moe_sum_kernel(const float* __restrict__ eo,
                                                      float* __restrict__ xio) {
    const int row = blockIdx.x, tid = threadIdx.x;
    for (int c = tid; c < CC; c += 256) {
        float s = 0.f;
        #pragma unroll
        for (int e2 = 0; e2 < EE; e2++)
            s += eo[((long)row*EE + e2)*CC + c];
        xio[(long)row*CC + c] += s;
    }
}

// ---------------------------------------------------------------------------
extern "C" void kernel_launch(void* const* d_in, const int* in_sizes, int n_in,
                              void* d_out, int out_size, void* d_ws, size_t ws_size,
                              hipStream_t stream) {
    const float* x     = (const float*)d_in[0];
    const float* ln1_g = (const float*)d_in[1];
    const float* ln1_b = (const float*)d_in[2];
    const float* ln2_g = (const float*)d_in[3];
    const float* ln2_b = (const float*)d_in[4];
    const float* wq    = (const float*)d_in[5];
    const float* wk    = (const float*)d_in[6];
    const float* wv    = (const float*)d_in[7];
    const float* wo    = (const float*)d_in[8];
    const float* sim   = (const float*)d_in[9];
    const float* thr   = (const float*)d_in[10];
    const float* w1    = (const float*)d_in[11];
    const float* w2    = (const float*)d_in[12];

    float* out_x      = (float*)d_out;
    float* out_scores = out_x + (long)NN*CC;
    float* out_eo     = out_scores + (long)NN*EE;
    float* out_kpt    = out_eo + (long)NN*EE*CC;

    const long MF = (long)NN*CC;     // 2M floats
    float* ws   = (float*)d_ws;
    float* h    = ws;                // LN1 out; reused as h2 fp32 after WO
    float* qb   = ws + MF;
    float* kb   = ws + 2*MF;
    float* vb   = ws + 3*MF;
    float* ao   = ws + 4*MF;
    __hip_bfloat16* h2b = (__hip_bfloat16*)(ws + 5*MF);              // 2M elems
    float* Opart = ws + 5*MF + MF/2;                                 // 2MF floats (attn)
    __hip_bfloat16* mid = (__hip_bfloat16*)(ws + 5*MF + MF/2);       // same region, used after merge
    __hip_bfloat16* w1t = (__hip_bfloat16*)(ws + 7*MF + MF/2);       // 4M elems
    __hip_bfloat16* w2t = (__hip_bfloat16*)(ws + 8*MF + MF/2);       // 4M elems
    float* maskb = ws + 9*MF + MF/2;                                  // 32K
    float* cn    = maskb + (long)NN*EE;                               // 16
    float* mpart = cn + 16;                                           // 64K
    float* lpart = mpart + 1024L*64;                                  // 64K

    // 0. expert weight transposes (fp32 -> bf16, [K][N] -> [N][K])
    {
        dim3 g1(II/32, CC/32, EE);
        transpose_f2b<<<g1, 256, 0, stream>>>(w1, (long)CC*II, w1t, (long)CC*II, CC, II);
        dim3 g2(CC/32, II/32, EE);
        transpose_f2b<<<g2, 256, 0, stream>>>(w2, (long)II*CC, w2t, (long)II*CC, II, CC);
    }

    // 1. LN1
    ln_kernel<<<NN, 256, 0, stream>>>(x, ln1_g, ln1_b, h, nullptr);

    // 2. QKV projections (bf16x3 split MFMA, fp32-accurate)
    dim3 gmm(CC/128, NN/64, 1);
    gemm_mfma32<0><<<gmm, 256, 0, stream>>>(h, wq, qb, NN, CC, CC, nullptr);
    gemm_mfma32<0><<<gmm, 256, 0, stream>>>(h, wk, kb, NN, CC, CC, nullptr);
    gemm_mfma32<0><<<gmm, 256, 0, stream>>>(h, wv, vb, NN, CC, CC, nullptr);

    // 3. causal attention, kt-split (balanced) + merge
    {
        dim3 gattn(32, HH, BB);
        attn_split<<<gattn, 256, 0, stream>>>(qb, kb, vb, Opart, mpart, lpart);
        dim3 gmerge(16, HH, BB);
        attn_merge<<<gmerge, 256, 0, stream>>>(Opart, mpart, lpart, ao);
    }

    // 4. output projection + residual -> d_out x slot
    gemm_mfma32<1><<<gmm, 256, 0, stream>>>(ao, wo, out_x, NN, CC, CC, x);

    // 5. LN2 -> h (fp32 for router) + h2b (bf16 for expert GEMM)
    ln_kernel<<<NN, 256, 0, stream>>>(out_x, ln2_g, ln2_b, h, h2b);

    // 6. router (fp32-exact so mask matches reference bit-stably)
    colnorm_kernel<<<EE, 256, 0, stream>>>(sim, cn);
    scores_kernel<<<NN, 256, 0, stream>>>(h, sim, cn, thr, out_scores, out_kpt, maskb);

    // 7. expert GEMM 1 (MFMA bf16): mid[e] = gelu(h2 @ w1[e]) -> bf16
    {
        dim3 g(II/128, NN/128, EE);
        gemm_mfma<0><<<g, 256, 0, stream>>>(h2b, 0, w1t, (long)II*CC,
                                            mid, (long)NN*II, II,
                                            NN, II, CC, nullptr);
    }

    // 8. expert GEMM 2 (MFMA bf16): eo[n,e,:] = (mid[e] @ w2[e]) * mask[n,e]
    {
        dim3 g(CC/128, NN/128, EE);
        gemm_mfma<1><<<g, 256, 0, stream>>>(mid, (long)NN*II, w2t, (long)II*CC,
                                            out_eo, (long)CC, EE*CC,
                                            NN, CC, II, maskb);
    }

    // 9. final = sum_e eo; x += final (in place on d_out)
    moe_sum_kernel<<<NN, 256, 0, stream>>>(out_eo, out_x);
}

// Round 5
// 760.031 us; speedup vs baseline: 2.6304x; 1.0921x over previous
//
#include <hip/hip_runtime.h>
#include <hip/hip_bf16.h>
#include <math.h>

// Problem constants
#define BB 2
#define TT 1024
#define CC 1024
#define HH 16
#define DD 64
#define EE 16
#define II 256
#define NN (BB*TT)          // 2048 tokens
#define EPSLN 1e-5f
#define LDA 72              // bf16 LDS row stride: 144B rows, 16B-aligned

typedef __attribute__((ext_vector_type(8))) short short8;
typedef __attribute__((ext_vector_type(4))) float f32x4;

__device__ inline void splitbf(float x, short& hi, short& lo) {
    __hip_bfloat16 h = __float2bfloat16(x);
    float hf = __bfloat162float(h);
    __hip_bfloat16 l = __float2bfloat16(x - hf);
    hi = *(short*)&h;
    lo = *(short*)&l;
}

// ---------------------------------------------------------------------------
// LayerNorm: one block per row of 1024. Optional bf16 secondary output.
// ---------------------------------------------------------------------------
__global__ __launch_bounds__(256) void ln_kernel(const float* __restrict__ x,
                                                 const float* __restrict__ g,
                                                 const float* __restrict__ bta,
                                                 float* __restrict__ out,
                                                 __hip_bfloat16* __restrict__ outb) {
    const int row = blockIdx.x, tid = threadIdx.x;
    __shared__ float r1[256], r2[256];
    const float* xr = x + (long)row * CC;
    float4 xv = ((const float4*)xr)[tid];
    float s  = xv.x + xv.y + xv.z + xv.w;
    float q2 = xv.x*xv.x + xv.y*xv.y + xv.z*xv.z + xv.w*xv.w;
    r1[tid] = s; r2[tid] = q2; __syncthreads();
    for (int st = 128; st > 0; st >>= 1) {
        if (tid < st) { r1[tid] += r1[tid+st]; r2[tid] += r2[tid+st]; }
        __syncthreads();
    }
    const float mu  = r1[0] * (1.f/CC);
    const float var = r2[0] * (1.f/CC) - mu*mu;
    const float rs  = rsqrtf(var + EPSLN);
    float4 gv = ((const float4*)g)[tid];
    float4 bv = ((const float4*)bta)[tid];
    float4 ov;
    ov.x = (xv.x-mu)*rs*gv.x + bv.x;
    ov.y = (xv.y-mu)*rs*gv.y + bv.y;
    ov.z = (xv.z-mu)*rs*gv.z + bv.z;
    ov.w = (xv.w-mu)*rs*gv.w + bv.w;
    ((float4*)(out + (long)row * CC))[tid] = ov;
    if (outb) {
        __hip_bfloat16* p = outb + (long)row * CC + tid*4;
        p[0] = __float2bfloat16(ov.x); p[1] = __float2bfloat16(ov.y);
        p[2] = __float2bfloat16(ov.z); p[3] = __float2bfloat16(ov.w);
    }
}

// ---------------------------------------------------------------------------
// fp32-accurate MFMA GEMM via bf16x3 split (AhBh + AhBl + AlBh).
// C[M,N] = A[M,K] * W[K,N] (+resid). Tile 64Mx128N, BK=32, 4 waves.
// EPI: 0 = plain, 1 = +resid
// ---------------------------------------------------------------------------
template<int EPI>
__global__ __launch_bounds__(256, 2) void gemm_mfma32(
        const float* __restrict__ A,
        const float* __restrict__ W,
        float* __restrict__ Cp,
        int M, int N, int K,
        const float* __restrict__ resid) {
    __shared__ __hip_bfloat16 Ash[64][40], Asl[64][40];
    __shared__ __hip_bfloat16 Bsh[128][40], Bsl[128][40];
    const int n0 = blockIdx.x * 128, m0 = blockIdx.y * 64;
    const int tid = threadIdx.x;
    const int wave = tid >> 6, lane = tid & 63;
    const int wm = (wave >> 1) * 32, wn = (wave & 1) * 64;
    const int l15 = lane & 15, quad = lane >> 4;

    f32x4 acc[2][4] = {};

    for (int k0 = 0; k0 < K; k0 += 32) {
        {
            const int r = tid >> 2, kg = (tid & 3) * 8;
            const float* ap = A + (long)(m0 + r)*K + k0 + kg;
            float4 x0 = *(const float4*)ap, x1 = *(const float4*)(ap + 4);
            float xs[8] = {x0.x,x0.y,x0.z,x0.w,x1.x,x1.y,x1.z,x1.w};
            short8 hv, lv;
            #pragma unroll
            for (int j = 0; j < 8; j++) { short h,l; splitbf(xs[j], h, l); hv[j]=h; lv[j]=l; }
            *(short8*)&Ash[r][kg] = hv;
            *(short8*)&Asl[r][kg] = lv;
        }
        #pragma unroll
        for (int it = 0; it < 2; it++) {
            const int idx = tid + it*256;
            const int kk = idx >> 4;
            const int n8 = (idx & 15) * 8;
            const float* wp = W + (long)(k0 + kk)*N + n0 + n8;
            float4 x0 = *(const float4*)wp, x1 = *(const float4*)(wp + 4);
            float xs[8] = {x0.x,x0.y,x0.z,x0.w,x1.x,x1.y,x1.z,x1.w};
            #pragma unroll
            for (int j = 0; j < 8; j++) {
                short h,l; splitbf(xs[j], h, l);
                *(short*)&Bsh[n8+j][kk] = h;
                *(short*)&Bsl[n8+j][kk] = l;
            }
        }
        __syncthreads();
        short8 ah[2], al[2], bh[4], bl[4];
        #pragma unroll
        for (int mi = 0; mi < 2; mi++) {
            ah[mi] = *(const short8*)&Ash[wm + mi*16 + l15][quad*8];
            al[mi] = *(const short8*)&Asl[wm + mi*16 + l15][quad*8];
        }
        #pragma unroll
        for (int ni = 0; ni < 4; ni++) {
            bh[ni] = *(const short8*)&Bsh[wn + ni*16 + l15][quad*8];
            bl[ni] = *(const short8*)&Bsl[wn + ni*16 + l15][quad*8];
        }
        #pragma unroll
        for (int mi = 0; mi < 2; mi++)
            #pragma unroll
            for (int ni = 0; ni < 4; ni++) {
                acc[mi][ni] = __builtin_amdgcn_mfma_f32_16x16x32_bf16(ah[mi], bh[ni], acc[mi][ni], 0,0,0);
                acc[mi][ni] = __builtin_amdgcn_mfma_f32_16x16x32_bf16(ah[mi], bl[ni], acc[mi][ni], 0,0,0);
                acc[mi][ni] = __builtin_amdgcn_mfma_f32_16x16x32_bf16(al[mi], bh[ni], acc[mi][ni], 0,0,0);
            }
        __syncthreads();
    }

    #pragma unroll
    for (int mi = 0; mi < 2; mi++)
        #pragma unroll
        for (int r = 0; r < 4; r++) {
            const int row = m0 + wm + mi*16 + quad*4 + r;
            #pragma unroll
            for (int ni = 0; ni < 4; ni++) {
                const int col = n0 + wn + ni*16 + l15;
                float val = acc[mi][ni][r];
                if (EPI == 1) val += resid[(long)row*N + col];
                Cp[(long)row*N + col] = val;
            }
        }
}

// ---------------------------------------------------------------------------
// bf16 MFMA GEMM (expert path): C = A[M,K] * Bt[N,K]^T, batched over z.
// EPI: 0 = exact gelu -> bf16 out; 1 = *mask -> fp32 strided out
// ---------------------------------------------------------------------------
template<int EPI>
__global__ __launch_bounds__(256) void gemm_mfma(
        const __hip_bfloat16* __restrict__ A, long sAe,
        const __hip_bfloat16* __restrict__ Bt, long sBe,
        void* __restrict__ Cp, long sCe, int ldc,
        int M, int N, int K,
        const float* __restrict__ mask) {
    constexpr int LDK = 40;
    __shared__ __hip_bfloat16 As[128][LDK];
    __shared__ __hip_bfloat16 Bs[128][LDK];
    const int e = blockIdx.z;
    A  += (long)e * sAe;
    Bt += (long)e * sBe;
    const int n0 = blockIdx.x * 128, m0 = blockIdx.y * 128;
    const int tid = threadIdx.x;
    const int wave = tid >> 6, lane = tid & 63;
    const int wm = (wave >> 1) * 64, wn = (wave & 1) * 64;
    const int l15 = lane & 15, quad = lane >> 4;

    f32x4 acc[4][4] = {};

    for (int k0 = 0; k0 < K; k0 += 32) {
        #pragma unroll
        for (int it = 0; it < 2; it++) {
            int idx = tid + it*256;
            int r = idx >> 2, kg = idx & 3;
            short8 av = *(const short8*)(A  + (long)(m0 + r)*K + k0 + kg*8);
            short8 bv = *(const short8*)(Bt + (long)(n0 + r)*K + k0 + kg*8);
            *(short8*)&As[r][kg*8] = av;
            *(short8*)&Bs[r][kg*8] = bv;
        }
        __syncthreads();
        short8 af[4], bff[4];
        #pragma unroll
        for (int i = 0; i < 4; i++) {
            af[i]  = *(const short8*)&As[wm + i*16 + l15][quad*8];
            bff[i] = *(const short8*)&Bs[wn + i*16 + l15][quad*8];
        }
        #pragma unroll
        for (int mi = 0; mi < 4; mi++)
            #pragma unroll
            for (int ni = 0; ni < 4; ni++)
                acc[mi][ni] = __builtin_amdgcn_mfma_f32_16x16x32_bf16(
                                  af[mi], bff[ni], acc[mi][ni], 0, 0, 0);
        __syncthreads();
    }

    #pragma unroll
    for (int mi = 0; mi < 4; mi++) {
        #pragma unroll
        for (int r = 0; r < 4; r++) {
            const int row = m0 + wm + mi*16 + quad*4 + r;
            float mv = 0.f;
            if (EPI == 1) mv = mask[(long)row*EE + e];
            #pragma unroll
            for (int ni = 0; ni < 4; ni++) {
                const int col = n0 + wn + ni*16 + l15;
                float val = acc[mi][ni][r];
                if (EPI == 0) {
                    val = 0.5f*val*(1.f + erff(val*0.70710678118f));
                    ((__hip_bfloat16*)Cp)[(long)e*sCe + (long)row*ldc + col] =
                        __float2bfloat16(val);
                } else {
                    ((float*)Cp)[(long)e*sCe + (long)row*ldc + col] = val*mv;
                }
            }
        }
    }
}

// ---------------------------------------------------------------------------
// Tiled fp32 -> bf16 transpose for expert weights.
// ---------------------------------------------------------------------------
__global__ __launch_bounds__(256) void transpose_f2b(const float* __restrict__ W, long sWe,
                                                     __hip_bfloat16* __restrict__ Wt, long sWte,
                                                     int K, int N) {
    const int e = blockIdx.z;
    W  += (long)e * sWe;
    Wt += (long)e * sWte;
    const int n0 = blockIdx.x * 32, k0 = blockIdx.y * 32;
    __shared__ float t[32][33];
    const int tx = threadIdx.x & 31, ty = threadIdx.x >> 5;
    #pragma unroll
    for (int i = 0; i < 4; i++)
        t[ty + i*8][tx] = W[(long)(k0 + ty + i*8)*N + n0 + tx];
    __syncthreads();
    #pragma unroll
    for (int i = 0; i < 4; i++)
        Wt[(long)(n0 + ty + i*8)*K + k0 + tx] = __float2bfloat16(t[tx][ty + i*8]);
}

// ---------------------------------------------------------------------------
// Flash attention with bf16x3 MFMA for QK^T and PV. kt-split for balance.
// Block = (b, h, qt, half). Q A-frags from global (no LDS). K staged split
// [key][d]; V staged transposed split [d][kk]; P overwrites K region
// (C/D -> A layout round-trip). Online softmax in registers via width-16
// shuffles (C/D rows = quad*4+reg). Unnormalized O + (m,l) partials out.
// ---------------------------------------------------------------------------
__global__ __launch_bounds__(256, 4) void attn_split(const float* __restrict__ q,
                                                     const float* __restrict__ k,
                                                     const float* __restrict__ v,
                                                     float* __restrict__ Opart,
                                                     float* __restrict__ mpart,
                                                     float* __restrict__ lpart) {
    __shared__ __hip_bfloat16 KPh[64][LDA], KPl[64][LDA];   // K, then P
    __shared__ __hip_bfloat16 Vth[64][LDA], Vtl[64][LDA];   // V^T [d][kk]

    const int bx = blockIdx.x;                 // 0..31, heavy qt first
    const int qt = 15 - (bx >> 1), half = bx & 1;
    const int h = blockIdx.y, b = blockIdx.z;
    const int tid = threadIdx.x;
    const int wave = tid >> 6, lane = tid & 63;
    const int l15 = lane & 15, quad = lane >> 4;
    const int wm = wave * 16;                  // wave's 16 q-rows in the 64-tile
    const long base = (long)b * TT * CC + (long)h * DD;
    const int pidx = ((b*HH + h)*16 + qt)*2 + half;
    float* Op = Opart + (long)pidx * 4096;

    const int n_kt = qt + 1, mid_kt = (n_kt + 1) >> 1;
    const int kt_lo = half ? mid_kt : 0;
    const int kt_hi = half ? n_kt   : mid_kt;

    if (kt_lo >= kt_hi) {      // empty half (qt=0): neutral partials
        for (int i = tid; i < 64*64; i += 256) Op[i] = 0.f;
        if (tid < 64) { mpart[(long)pidx*64 + tid] = -1e30f; lpart[(long)pidx*64 + tid] = 0.f; }
        return;
    }

    // Q A-fragments from global, split: row = qt*64 + wm + l15, k = kc*32+quad*8
    short8 qh[2], ql[2];
    {
        const float* qrow = q + base + (long)(qt*64 + wm + l15)*CC;
        #pragma unroll
        for (int kc = 0; kc < 2; kc++) {
            const float* p = qrow + kc*32 + quad*8;
            float4 x0 = *(const float4*)p, x1 = *(const float4*)(p + 4);
            float xs[8] = {x0.x,x0.y,x0.z,x0.w,x1.x,x1.y,x1.z,x1.w};
            #pragma unroll
            for (int j = 0; j < 8; j++) { short hh,ll; splitbf(xs[j],hh,ll); qh[kc][j]=hh; ql[kc][j]=ll; }
        }
    }

    f32x4 oacc[4] = {};            // 4 d-tiles, rows = quad*4+reg
    float m_run[4], l_run[4];
    #pragma unroll
    for (int r = 0; r < 4; r++) { m_run[r] = -1e30f; l_run[r] = 0.f; }

    for (int kt = kt_lo; kt < kt_hi; kt++) {
        __syncthreads();           // prev-iter PV reads of KP/Vt done
        // stage K split: [key r][d]
        #pragma unroll
        for (int it = 0; it < 2; it++) {
            int idx = tid + it*256;
            int r = idx >> 3, g = (idx & 7)*8;
            const float* kp = k + base + (long)(kt*64 + r)*CC + g;
            float4 x0 = *(const float4*)kp, x1 = *(const float4*)(kp + 4);
            float xs[8] = {x0.x,x0.y,x0.z,x0.w,x1.x,x1.y,x1.z,x1.w};
            short8 hv, lv;
            #pragma unroll
            for (int j = 0; j < 8; j++) { short hh,ll; splitbf(xs[j],hh,ll); hv[j]=hh; lv[j]=ll; }
            *(short8*)&KPh[r][g] = hv;
            *(short8*)&KPl[r][g] = lv;
        }
        // stage V transposed split: read 8 d at token kk, scatter rows d
        #pragma unroll
        for (int it = 0; it < 2; it++) {
            int idx = tid + it*256;
            int kk = idx >> 3, g = (idx & 7)*8;
            const float* vp = v + base + (long)(kt*64 + kk)*CC + g;
            float4 x0 = *(const float4*)vp, x1 = *(const float4*)(vp + 4);
            float xs[8] = {x0.x,x0.y,x0.z,x0.w,x1.x,x1.y,x1.z,x1.w};
            #pragma unroll
            for (int j = 0; j < 8; j++) {
                short hh,ll; splitbf(xs[j],hh,ll);
                *(short*)&Vth[g+j][kk] = hh;
                *(short*)&Vtl[g+j][kk] = ll;
            }
        }
        __syncthreads();

        // QK^T via MFMA: 4 key-tiles x 2 k-chunks x 3 split terms
        f32x4 s[4] = {};
        #pragma unroll
        for (int nt = 0; nt < 4; nt++)
            #pragma unroll
            for (int kc = 0; kc < 2; kc++) {
                short8 bh = *(const short8*)&KPh[nt*16 + l15][kc*32 + quad*8];
                short8 bl = *(const short8*)&KPl[nt*16 + l15][kc*32 + quad*8];
                s[nt] = __builtin_amdgcn_mfma_f32_16x16x32_bf16(qh[kc], bh, s[nt], 0,0,0);
                s[nt] = __builtin_amdgcn_mfma_f32_16x16x32_bf16(qh[kc], bl, s[nt], 0,0,0);
                s[nt] = __builtin_amdgcn_mfma_f32_16x16x32_bf16(ql[kc], bh, s[nt], 0,0,0);
            }

        // online softmax in regs; row = wm + quad*4 + r, col = nt*16 + l15
        const bool diag = (kt == qt);
        float alpha[4];
        float pr[4][4];
        #pragma unroll
        for (int r = 0; r < 4; r++) {
            const int rowg = wm + quad*4 + r;
            float sv[4], mx = -1e30f;
            #pragma unroll
            for (int nt = 0; nt < 4; nt++) {
                float val = s[nt][r] * 0.125f;
                if (diag && (nt*16 + l15) > rowg) val = -1e30f;
                sv[nt] = val;
                mx = fmaxf(mx, val);
            }
            #pragma unroll
            for (int off = 1; off < 16; off <<= 1) mx = fmaxf(mx, __shfl_xor(mx, off, 16));
            const float mnew = fmaxf(m_run[r], mx);
            alpha[r] = __expf(m_run[r] - mnew);
            float rs = 0.f;
            #pragma unroll
            for (int nt = 0; nt < 4; nt++) {
                float p = __expf(sv[nt] - mnew);
                pr[r][nt] = p;
                rs += p;
            }
            #pragma unroll
            for (int off = 1; off < 16; off <<= 1) rs += __shfl_xor(rs, off, 16);
            l_run[r] = l_run[r]*alpha[r] + rs;
            m_run[r] = mnew;
        }
        __syncthreads();           // all QK reads of KP done -> overwrite as P

        // write P split into KP region: row = wm+quad*4+r, col = nt*16+l15
        #pragma unroll
        for (int r = 0; r < 4; r++)
            #pragma unroll
            for (int nt = 0; nt < 4; nt++) {
                short hh, ll; splitbf(pr[r][nt], hh, ll);
                *(short*)&KPh[wm + quad*4 + r][nt*16 + l15] = hh;
                *(short*)&KPl[wm + quad*4 + r][nt*16 + l15] = ll;
            }
        // no barrier: PV reads only this wave's own 16 P-rows

        // rescale O and accumulate PV via MFMA
        #pragma unroll
        for (int dt = 0; dt < 4; dt++)
            #pragma unroll
            for (int r = 0; r < 4; r++)
                oacc[dt][r] *= alpha[r];
        #pragma unroll
        for (int kc = 0; kc < 2; kc++) {
            short8 ph = *(const short8*)&KPh[wm + l15][kc*32 + quad*8];
            short8 pl = *(const short8*)&KPl[wm + l15][kc*32 + quad*8];
            #pragma unroll
            for (int dt = 0; dt < 4; dt++) {
                short8 vh = *(const short8*)&Vth[dt*16 + l15][kc*32 + quad*8];
                short8 vl = *(const short8*)&Vtl[dt*16 + l15][kc*32 + quad*8];
                oacc[dt] = __builtin_amdgcn_mfma_f32_16x16x32_bf16(ph, vh, oacc[dt], 0,0,0);
                oacc[dt] = __builtin_amdgcn_mfma_f32_16x16x32_bf16(ph, vl, oacc[dt], 0,0,0);
                oacc[dt] = __builtin_amdgcn_mfma_f32_16x16x32_bf16(pl, vh, oacc[dt], 0,0,0);
            }
        }
    }

    // store unnormalized O partial + (m,l)
    #pragma unroll
    for (int dt = 0; dt < 4; dt++)
        #pragma unroll
        for (int r = 0; r < 4; r++)
            Op[(wm + quad*4 + r)*64 + dt*16 + l15] = oacc[dt][r];
    if (l15 == 0) {
        #pragma unroll
        for (int r = 0; r < 4; r++) {
            mpart[(long)pidx*64 + wm + quad*4 + r] = m_run[r];
            lpart[(long)pidx*64 + wm + quad*4 + r] = l_run[r];
        }
    }
}

// ---------------------------------------------------------------------------
// Merge the two kt-half partials -> normalized attention output.
// ---------------------------------------------------------------------------
__global__ __launch_bounds__(256) void attn_merge(const float* __restrict__ Opart,
                                                  const float* __restrict__ mpart,
                                                  const float* __restrict__ lpart,
                                                  float* __restrict__ ao) {
    const int qt = blockIdx.x, h = blockIdx.y, b = blockIdx.z;
    const int pA = ((b*HH + h)*16 + qt)*2, pB = pA + 1;
    const int tid = threadIdx.x;
    const int r = tid >> 2, c0 = (tid & 3) * 16;
    const float mA = mpart[(long)pA*64 + r], mB = mpart[(long)pB*64 + r];
    const float lA = lpart[(long)pA*64 + r], lB = lpart[(long)pB*64 + r];
    const float M  = fmaxf(mA, mB);
    const float wA = __expf(mA - M), wB = __expf(mB - M);
    const float inv = 1.f / (lA*wA + lB*wB);
    const float* OA = Opart + (long)pA*4096 + r*64 + c0;
    const float* OB = Opart + (long)pB*4096 + r*64 + c0;
    float* dst = ao + (long)b*TT*CC + (long)(qt*64 + r)*CC + h*DD + c0;
    #pragma unroll
    for (int j = 0; j < 16; j += 4) {
        float4 oa = *(const float4*)(OA + j);
        float4 ob = *(const float4*)(OB + j);
        float4 o;
        o.x = (oa.x*wA + ob.x*wB)*inv; o.y = (oa.y*wA + ob.y*wB)*inv;
        o.z = (oa.z*wA + ob.z*wB)*inv; o.w = (oa.w*wA + ob.w*wB)*inv;
        *(float4*)(dst + j) = o;
    }
}

// ---------------------------------------------------------------------------
// Column norms of sim_matrix [C, E]
// ---------------------------------------------------------------------------
__global__ __launch_bounds__(256) void colnorm_kernel(const float* __restrict__ sim,
                                                      float* __restrict__ cn) {
    const int e = blockIdx.x, tid = threadIdx.x;
    __shared__ float red[256];
    float s = 0.f;
    for (int c = tid; c < CC; c += 256) {
        float vv = sim[(long)c*EE + e];
        s += vv*vv;
    }
    red[tid] = s; __syncthreads();
    for (int st = 128; st > 0; st >>= 1) {
        if (tid < st) red[tid] += red[tid+st];
        __syncthreads();
    }
    if (tid == 0) cn[e] = sqrtf(red[0]);
}

// ---------------------------------------------------------------------------
// Router: scores, mask, k_per_token (fp32-exact). One block per token.
// ---------------------------------------------------------------------------
__global__ __launch_bounds__(256) void scores_kernel(const float* __restrict__ h2,
                                                     const float* __restrict__ sim,
                                                     const float* __restrict__ cn,
                                                     const float* __restrict__ thr,
                                                     float* __restrict__ scores,
                                                     float* __restrict__ kpt,
                                                     float* __restrict__ maskb) {
    const int row = blockIdx.x, tid = threadIdx.x;
    __shared__ float red[256*17];
    float acc[17] = {};
    for (int c = tid; c < CC; c += 256) {
        const float xv = h2[(long)row*CC + c];
        acc[16] += xv*xv;
        const float* sr = sim + (long)c*EE;
        #pragma unroll
        for (int e2 = 0; e2 < EE; e2++) acc[e2] += xv*sr[e2];
    }
    #pragma unroll
    for (int e2 = 0; e2 < 17; e2++) red[tid*17 + e2] = acc[e2];
    __syncthreads();
    for (int st = 128; st > 0; st >>= 1) {
        if (tid < st)
            for (int e2 = 0; e2 < 17; e2++) red[tid*17+e2] += red[(tid+st)*17+e2];
        __syncthreads();
    }
    if (tid < EE) {
        const float nrm = sqrtf(red[16]);
        const float sc  = red[tid] / (nrm * cn[tid]);
        scores[(long)row*EE + tid] = sc;
        const float mkv = sc > thr[0] ? 1.f : 0.f;
        maskb[(long)row*EE + tid] = mkv;
        red[tid] = mkv;
    }
    __syncthreads();
    if (tid == 0) {
        float c2 = 0.f;
        for (int e2 = 0; e2 < EE; e2++) c2 += red[e2];
        kpt[row] = c2;
    }
}

// ---------------------------------------------------------------------------
// final[n,c] = sum_e eo[n,e,c]; x_out += final, in place
// ---------------------------------------------------------------------------
__global__ __launch_bounds__(256) void moe_sum_kernel(const float* __restrict__ eo,
                                                      float* __restrict__ xio) {
    const int row = blockIdx.x, tid = threadIdx.x;
    for (int c = tid; c < CC; c += 256) {
        float s = 0.f;
        #pragma unroll
        for (int e2 = 0; e2 < EE; e2++)
            s += eo[((long)row*EE + e2)*CC + c];
        xio[(long)row*CC + c] += s;
    }
}

// ---------------------------------------------------------------------------
extern "C" void kernel_launch(void* const* d_in, const int* in_sizes, int n_in,
                              void* d_out, int out_size, void* d_ws, size_t ws_size,
                              hipStream_t stream) {
    const float* x     = (const float*)d_in[0];
    const float* ln1_g = (const float*)d_in[1];
    const float* ln1_b = (const float*)d_in[2];
    const float* ln2_g = (const float*)d_in[3];
    const float* ln2_b = (const float*)d_in[4];
    const float* wq    = (const float*)d_in[5];
    const float* wk    = (const float*)d_in[6];
    const float* wv    = (const float*)d_in[7];
    const float* wo    = (const float*)d_in[8];
    const float* sim   = (const float*)d_in[9];
    const float* thr   = (const float*)d_in[10];
    const float* w1    = (const float*)d_in[11];
    const float* w2    = (const float*)d_in[12];

    float* out_x      = (float*)d_out;
    float* out_scores = out_x + (long)NN*CC;
    float* out_eo     = out_scores + (long)NN*EE;
    float* out_kpt    = out_eo + (long)NN*EE*CC;

    const long MF = (long)NN*CC;     // 2M floats
    float* ws   = (float*)d_ws;
    float* h    = ws;                // LN1 out; reused as h2 fp32 after WO
    float* qb   = ws + MF;
    float* kb   = ws + 2*MF;
    float* vb   = ws + 3*MF;
    float* ao   = ws + 4*MF;
    __hip_bfloat16* h2b = (__hip_bfloat16*)(ws + 5*MF);              // 2M elems
    float* Opart = ws + 5*MF + MF/2;                                 // 2MF floats (attn)
    __hip_bfloat16* mid = (__hip_bfloat16*)(ws + 5*MF + MF/2);       // same region, used after merge
    __hip_bfloat16* w1t = (__hip_bfloat16*)(ws + 7*MF + MF/2);       // 4M elems
    __hip_bfloat16* w2t = (__hip_bfloat16*)(ws + 8*MF + MF/2);       // 4M elems
    float* maskb = ws + 9*MF + MF/2;                                  // 32K
    float* cn    = maskb + (long)NN*EE;                               // 16
    float* mpart = cn + 16;                                           // 64K
    float* lpart = mpart + 1024L*64;                                  // 64K

    // 0. expert weight transposes (fp32 -> bf16, [K][N] -> [N][K])
    {
        dim3 g1(II/32, CC/32, EE);
        transpose_f2b<<<g1, 256, 0, stream>>>(w1, (long)CC*II, w1t, (long)CC*II, CC, II);
        dim3 g2(CC/32, II/32, EE);
        transpose_f2b<<<g2, 256, 0, stream>>>(w2, (long)II*CC, w2t, (long)II*CC, II, CC);
    }

    // 1. LN1
    ln_kernel<<<NN, 256, 0, stream>>>(x, ln1_g, ln1_b, h, nullptr);

    // 2. QKV projections (bf16x3 split MFMA, fp32-accurate)
    dim3 gmm(CC/128, NN/64, 1);
    gemm_mfma32<0><<<gmm, 256, 0, stream>>>(h, wq, qb, NN, CC, CC, nullptr);
    gemm_mfma32<0><<<gmm, 256, 0, stream>>>(h, wk, kb, NN, CC, CC, nullptr);
    gemm_mfma32<0><<<gmm, 256, 0, stream>>>(h, wv, vb, NN, CC, CC, nullptr);

    // 3. causal attention (MFMA flash, kt-split) + merge
    {
        dim3 gattn(32, HH, BB);
        attn_split<<<gattn, 256, 0, stream>>>(qb, kb, vb, Opart, mpart, lpart);
        dim3 gmerge(16, HH, BB);
        attn_merge<<<gmerge, 256, 0, stream>>>(Opart, mpart, lpart, ao);
    }

    // 4. output projection + residual -> d_out x slot
    gemm_mfma32<1><<<gmm, 256, 0, stream>>>(ao, wo, out_x, NN, CC, CC, x);

    // 5. LN2 -> h (fp32 for router) + h2b (bf16 for expert GEMM)
    ln_kernel<<<NN, 256, 0, stream>>>(out_x, ln2_g, ln2_b, h, h2b);

    // 6. router (fp32-exact so mask matches reference bit-stably)
    colnorm_kernel<<<EE, 256, 0, stream>>>(sim, cn);
    scores_kernel<<<NN, 256, 0, stream>>>(h, sim, cn, thr, out_scores, out_kpt, maskb);

    // 7. expert GEMM 1 (MFMA bf16): mid[e] = gelu(h2 @ w1[e]) -> bf16
    {
        dim3 g(II/128, NN/128, EE);
        gemm_mfma<0><<<g, 256, 0, stream>>>(h2b, 0, w1t, (long)II*CC,
                                            mid, (long)NN*II, II,
                                            NN, II, CC, nullptr);
    }

    // 8. expert GEMM 2 (MFMA bf16): eo[n,e,:] = (mid[e] @ w2[e]) * mask[n,e]
    {
        dim3 g(CC/128, NN/128, EE);
        gemm_mfma<1><<<g, 256, 0, stream>>>(mid, (long)NN*II, w2t, (long)II*CC,
                                            out_eo, (long)CC, EE*CC,
                                            NN, CC, II, maskb);
    }

    // 9. final = sum_e eo; x += final (in place on d_out)
    moe_sum_kernel<<<NN, 256, 0, stream>>>(out_eo, out_x);
}